// Round 3
// baseline (3790.704 us; speedup 1.0000x reference)
//
#include <hip/hip_runtime.h>
#include <hip/hip_fp16.h>

#define NNODES 100000
#define NEDGES 1600000
#define NGRAPH 512
#define DIM    100
#define DP     128
#define SLICES 7            // 7 column slices x 16 cols = 112 cols (100 real + 12 pad)
#define NCOLS  112
#define EPSBN  1e-5f
#define NBUK   ((NNODES + 255) >> 8)
#define BINCH  8192
#define CHNODES 16          // nodes per work-queue chunk in prop

typedef _Float16 half8 __attribute__((ext_vector_type(8)));
typedef float floatx4 __attribute__((ext_vector_type(4)));

// sliced feature layout: addr(node, col) = ((col>>4)*N + node)*16 + (col&15)  [halves]

// ---------------- pass 0: per-chunk bucket counts ----------------
__global__ __launch_bounds__(256) void bin_count_kernel(const int* __restrict__ dst,
                                                        int* __restrict__ btotal, int e) {
    __shared__ int lc[NBUK];
    int tid = threadIdx.x;
    int base = blockIdx.x * BINCH;
    int m = e - base; if (m > BINCH) m = BINCH;
    for (int b = tid; b < NBUK; b += 256) lc[b] = 0;
    __syncthreads();
    for (int j = tid; j < m; j += 256)
        atomicAdd(&lc[dst[base + j] >> 8], 1);
    __syncthreads();
    for (int b = tid; b < NBUK; b += 256)
        if (lc[b]) atomicAdd(&btotal[b], lc[b]);
}

// ---------------- bucket exclusive scan ----------------
__global__ void bucket_scan_kernel(const int* __restrict__ btotal, int* __restrict__ bbase,
                                   int* __restrict__ bcursor, int e) {
    __shared__ int s[512];
    int tid = threadIdx.x;
    int v = (tid < NBUK) ? btotal[tid] : 0;
    s[tid] = v; __syncthreads();
    for (int o = 1; o < 512; o <<= 1) {
        int t = (tid >= o) ? s[tid - o] : 0;
        __syncthreads();
        s[tid] += t;
        __syncthreads();
    }
    if (tid < NBUK) {
        int base = s[tid] - v;
        bbase[tid] = base;
        bcursor[tid] = base;
    }
    if (tid == 0) bbase[NBUK] = e;
}

// ---------------- pass 1: bin pairs bucket-major ----------------
__global__ __launch_bounds__(256) void bin_kernel(
        const int* __restrict__ src, const int* __restrict__ dst,
        int* __restrict__ bcursor, int2* __restrict__ gpairs, int e) {
    __shared__ int2 lpairs[BINCH];
    __shared__ int lcount[NBUK], lstart[NBUK], lcur[NBUK], gbase[NBUK];
    int tid = threadIdx.x;
    int base = blockIdx.x * BINCH;
    int m = e - base; if (m > BINCH) m = BINCH;

    for (int b = tid; b < NBUK; b += 256) lcount[b] = 0;
    __syncthreads();
    for (int j = tid; j < m; j += 256)
        atomicAdd(&lcount[dst[base + j] >> 8], 1);
    __syncthreads();
    if (tid == 0) {
        int acc = 0;
        for (int b = 0; b < NBUK; b++) {
            lstart[b] = acc;
            lcur[b] = acc;
            acc += lcount[b];
        }
    }
    __syncthreads();
    for (int b = tid; b < NBUK; b += 256)
        gbase[b] = atomicAdd(&bcursor[b], lcount[b]);
    for (int j = tid; j < m; j += 256) {
        int s = src[base + j], d = dst[base + j];
        int p = atomicAdd(&lcur[d >> 8], 1);
        lpairs[p] = make_int2(s, d);
    }
    __syncthreads();
    for (int j = tid; j < m; j += 256) {
        int2 pr = lpairs[j];
        int b = pr.y >> 8;
        gpairs[gbase[b] + (j - lstart[b])] = pr;
    }
}

// ---------------- pass 2: fused per-bucket build ----------------
__global__ __launch_bounds__(256) void bucket_build_kernel(
        const int2* __restrict__ gpairs, const int* __restrict__ bbase,
        int* __restrict__ off, int* __restrict__ ssorted,
        float* __restrict__ dsl, float* __restrict__ dnsl, int n, int e) {
    __shared__ int cnt[256];
    __shared__ int sc[256];
    int b = blockIdx.x, tid = threadIdx.x;
    int node0 = b << 8;
    int e0 = bbase[b], e1 = bbase[b + 1];

    cnt[tid] = 0;
    __syncthreads();
    for (int j = e0 + tid; j < e1; j += 256)
        atomicAdd(&cnt[gpairs[j].y & 255], 1);
    __syncthreads();

    int c = cnt[tid];
    sc[tid] = c; __syncthreads();
    for (int o = 1; o < 256; o <<= 1) {
        int t = (tid >= o) ? sc[tid - o] : 0;
        __syncthreads();
        sc[tid] += t;
        __syncthreads();
    }
    int excl = sc[tid] - c;

    int node = node0 + tid;
    if (node < n) {
        off[node] = e0 + excl;
        float cf = (float)c;
        dsl[node] = rsqrtf(cf + 1.0f);
        dnsl[node] = (c > 0) ? rsqrtf(cf) : 0.0f;
    }
    if (b == NBUK - 1 && tid == 0) off[n] = e;

    __syncthreads();
    cnt[tid] = e0 + excl;
    __syncthreads();
    for (int j = e0 + tid; j < e1; j += 256) {
        int2 pr = gpairs[j];
        int p = atomicAdd(&cnt[pr.y & 255], 1);
        ssorted[p] = pr.x;
    }
}

// ---------------- pack all 4 W into MFMA fragment order (one launch) ----------------
__global__ void packW4_kernel(const float* __restrict__ W1, const float* __restrict__ W2,
                              const float* __restrict__ W3, const float* __restrict__ W4,
                              _Float16* __restrict__ Wt1, _Float16* __restrict__ Wt2,
                              _Float16* __restrict__ Wt3, _Float16* __restrict__ Wt4) {
    int which = blockIdx.x >> 6;          // 64 blocks per weight
    int idx = (blockIdx.x & 63) * 256 + threadIdx.x;
    const float* W = (which == 0) ? W1 : (which == 1) ? W2 : (which == 2) ? W3 : W4;
    _Float16* Wt  = (which == 0) ? Wt1 : (which == 1) ? Wt2 : (which == 2) ? Wt3 : Wt4;
    int K = (which == 0) ? 128 : DIM;
    int j = idx & 7;
    int l = (idx >> 3) & 63;
    int c = idx >> 9;
    int t = c >> 2, k0 = c & 3;
    int nn = t * 16 + (l & 15);
    int k = k0 * 32 + (l >> 4) * 8 + j;
    float v = (k < K && nn < DIM) ? W[k * DIM + nn] : 0.f;
    Wt[idx] = (_Float16)v;
}

// ---------------- pad biases to 128 ----------------
__global__ void padb_kernel(const float* __restrict__ b1, const float* __restrict__ b2,
                            float* __restrict__ b1p, float* __restrict__ b2p) {
    int c = threadIdx.x;
    b1p[c] = (c < DIM) ? b1[c] : 0.f;
    b2p[c] = (c < DIM) ? b2[c] : 0.f;
}

// ---------------- sliced propagation (self-loop) : out = relu(dinv*sum + bias) ----------------
// Per-XCD slice affinity via HW_REG_XCC_ID + per-slice work queue (steal fallback for correctness).
__global__ __launch_bounds__(256) void prop_slice_kernel(
        const __half* __restrict__ pre, const int* __restrict__ ssorted,
        const int* __restrict__ off, const float* __restrict__ dinv,
        const float* __restrict__ bias, __half* __restrict__ outH,
        int* __restrict__ qcur, int n, int nch) {
    __shared__ int sh_slice, sh_chunk;
    int tid = threadIdx.x;
    if (tid == 0) {
        int s = (int)(__builtin_amdgcn_s_getreg(0xF814) & 7u);  // HW_REG_XCC_ID
        if (s > 6) s = 6;
        int c = atomicAdd(&qcur[s], 1);
        if (c >= nch) {
            c = -1;
            for (int t = 0; t < SLICES; t++) {
                int cc = atomicAdd(&qcur[t], 1);
                if (cc < nch) { s = t; c = cc; break; }
            }
        }
        sh_slice = s; sh_chunk = c;
    }
    __syncthreads();
    int slice = sh_slice, chunk = sh_chunk;
    if (chunk < 0) return;

    int lane = tid & 63;
    int w = tid >> 6;
    int p = lane >> 1, h = lane & 1;
    const __half* T = pre + (size_t)slice * n * 16;

    float4 b0 = *(const float4*)&bias[slice * 16 + h * 8];
    float4 b1v = *(const float4*)&bias[slice * 16 + h * 8 + 4];

    for (int jj = 0; jj < 4; jj++) {
        int node = chunk * CHNODES + w * 4 + jj;
        if (node >= n) break;
        int e0 = off[node], e1 = off[node + 1];
        int deg = e1 - e0;

        float acc[8];
#pragma unroll
        for (int i = 0; i < 8; i++) acc[i] = 0.f;

        auto addu = [&](uint4 u) {
            float2 f;
            f = __half22float2(*(__half2*)&u.x); acc[0] += f.x; acc[1] += f.y;
            f = __half22float2(*(__half2*)&u.y); acc[2] += f.x; acc[3] += f.y;
            f = __half22float2(*(__half2*)&u.z); acc[4] += f.x; acc[5] += f.y;
            f = __half22float2(*(__half2*)&u.w); acc[6] += f.x; acc[7] += f.y;
        };

        for (int base = 0; base < deg; base += 64) {
            int m = deg - base; if (m > 64) m = 64;
            int sidxv = (lane < m) ? __builtin_nontemporal_load(&ssorted[e0 + base + lane]) : 0;
            int sA = __shfl(sidxv, p);
            int sB = __shfl(sidxv, 32 + p);
            if (32 + p < m) {
                uint4 uA = *(const uint4*)&T[(size_t)sA * 16 + h * 8];
                uint4 uB = *(const uint4*)&T[(size_t)sB * 16 + h * 8];
                addu(uA); addu(uB);
            } else if (p < m) {
                uint4 uA = *(const uint4*)&T[(size_t)sA * 16 + h * 8];
                addu(uA);
            }
        }

#pragma unroll
        for (int i = 0; i < 8; i++) {
            acc[i] += __shfl_xor(acc[i], 2);
            acc[i] += __shfl_xor(acc[i], 4);
            acc[i] += __shfl_xor(acc[i], 8);
            acc[i] += __shfl_xor(acc[i], 16);
            acc[i] += __shfl_xor(acc[i], 32);
        }

        if (lane < 2) {
            addu(*(const uint4*)&T[(size_t)node * 16 + h * 8]);   // self-loop
            float dn = dinv[node];
            float o[8];
            o[0] = fmaxf(dn * acc[0] + b0.x, 0.f);
            o[1] = fmaxf(dn * acc[1] + b0.y, 0.f);
            o[2] = fmaxf(dn * acc[2] + b0.z, 0.f);
            o[3] = fmaxf(dn * acc[3] + b0.w, 0.f);
            o[4] = fmaxf(dn * acc[4] + b1v.x, 0.f);
            o[5] = fmaxf(dn * acc[5] + b1v.y, 0.f);
            o[6] = fmaxf(dn * acc[6] + b1v.z, 0.f);
            o[7] = fmaxf(dn * acc[7] + b1v.w, 0.f);
            __half2 p0 = __floats2half2_rn(o[0], o[1]);
            __half2 p1 = __floats2half2_rn(o[2], o[3]);
            __half2 p2 = __floats2half2_rn(o[4], o[5]);
            __half2 p3 = __floats2half2_rn(o[6], o[7]);
            uint4 u;
            u.x = *(unsigned int*)&p0;
            u.y = *(unsigned int*)&p1;
            u.z = *(unsigned int*)&p2;
            u.w = *(unsigned int*)&p3;
            *(uint4*)&outH[((size_t)slice * n + node) * 16 + h * 8] = u;
        }
    }
}

// ---------------- sliced ARMA prop: out = relu(dinv*sum + R), no self-loop ----------------
__global__ __launch_bounds__(256) void prop_arma_slice_kernel(
        const __half* __restrict__ pre, const int* __restrict__ ssorted,
        const int* __restrict__ off, const float* __restrict__ dinv,
        const __half* __restrict__ R, __half* __restrict__ outH,
        int* __restrict__ qcur, int n, int nch) {
    __shared__ int sh_slice, sh_chunk;
    int tid = threadIdx.x;
    if (tid == 0) {
        int s = (int)(__builtin_amdgcn_s_getreg(0xF814) & 7u);
        if (s > 6) s = 6;
        int c = atomicAdd(&qcur[s], 1);
        if (c >= nch) {
            c = -1;
            for (int t = 0; t < SLICES; t++) {
                int cc = atomicAdd(&qcur[t], 1);
                if (cc < nch) { s = t; c = cc; break; }
            }
        }
        sh_slice = s; sh_chunk = c;
    }
    __syncthreads();
    int slice = sh_slice, chunk = sh_chunk;
    if (chunk < 0) return;

    int lane = tid & 63;
    int w = tid >> 6;
    int p = lane >> 1, h = lane & 1;
    const __half* T = pre + (size_t)slice * n * 16;
    const __half* Rs = R + (size_t)slice * n * 16;

    for (int jj = 0; jj < 4; jj++) {
        int node = chunk * CHNODES + w * 4 + jj;
        if (node >= n) break;
        int e0 = off[node], e1 = off[node + 1];
        int deg = e1 - e0;

        float acc[8];
#pragma unroll
        for (int i = 0; i < 8; i++) acc[i] = 0.f;

        auto addu = [&](uint4 u) {
            float2 f;
            f = __half22float2(*(__half2*)&u.x); acc[0] += f.x; acc[1] += f.y;
            f = __half22float2(*(__half2*)&u.y); acc[2] += f.x; acc[3] += f.y;
            f = __half22float2(*(__half2*)&u.z); acc[4] += f.x; acc[5] += f.y;
            f = __half22float2(*(__half2*)&u.w); acc[6] += f.x; acc[7] += f.y;
        };

        for (int base = 0; base < deg; base += 64) {
            int m = deg - base; if (m > 64) m = 64;
            int sidxv = (lane < m) ? __builtin_nontemporal_load(&ssorted[e0 + base + lane]) : 0;
            int sA = __shfl(sidxv, p);
            int sB = __shfl(sidxv, 32 + p);
            if (32 + p < m) {
                uint4 uA = *(const uint4*)&T[(size_t)sA * 16 + h * 8];
                uint4 uB = *(const uint4*)&T[(size_t)sB * 16 + h * 8];
                addu(uA); addu(uB);
            } else if (p < m) {
                uint4 uA = *(const uint4*)&T[(size_t)sA * 16 + h * 8];
                addu(uA);
            }
        }

#pragma unroll
        for (int i = 0; i < 8; i++) {
            acc[i] += __shfl_xor(acc[i], 2);
            acc[i] += __shfl_xor(acc[i], 4);
            acc[i] += __shfl_xor(acc[i], 8);
            acc[i] += __shfl_xor(acc[i], 16);
            acc[i] += __shfl_xor(acc[i], 32);
        }

        if (lane < 2) {
            float dn = dinv[node];
            uint4 r4 = *(const uint4*)&Rs[(size_t)node * 16 + h * 8];
            float rr[8];
            float2 f;
            f = __half22float2(*(__half2*)&r4.x); rr[0] = f.x; rr[1] = f.y;
            f = __half22float2(*(__half2*)&r4.y); rr[2] = f.x; rr[3] = f.y;
            f = __half22float2(*(__half2*)&r4.z); rr[4] = f.x; rr[5] = f.y;
            f = __half22float2(*(__half2*)&r4.w); rr[6] = f.x; rr[7] = f.y;
            float o[8];
#pragma unroll
            for (int i = 0; i < 8; i++) o[i] = fmaxf(dn * acc[i] + rr[i], 0.f);
            __half2 p0 = __floats2half2_rn(o[0], o[1]);
            __half2 p1 = __floats2half2_rn(o[2], o[3]);
            __half2 p2 = __floats2half2_rn(o[4], o[5]);
            __half2 p3 = __floats2half2_rn(o[6], o[7]);
            uint4 u;
            u.x = *(unsigned int*)&p0;
            u.y = *(unsigned int*)&p1;
            u.z = *(unsigned int*)&p2;
            u.w = *(unsigned int*)&p3;
            *(uint4*)&outH[((size_t)slice * n + node) * 16 + h * 8] = u;
        }
    }
}

// ---------------- MFMA matmul, fp32 A (x input): C = (A@W) * rowscale -> fp16 sliced ----------------
__global__ __launch_bounds__(256) void matmul_a32_kernel(
        const float* __restrict__ A, const _Float16* __restrict__ WtF,
        const float* __restrict__ rowscale, __half* __restrict__ Ch, int M) {
    __shared__ char smraw[64 * 132 * 4];
    _Float16* Bs = (_Float16*)smraw;
    float* Ct = (float*)smraw;
    int tid = threadIdx.x;
    int wave = tid >> 6;
    int lane = tid & 63;
    int m16 = lane & 15;
    int quad = lane >> 4;
    long row0blk = (long)blockIdx.x * 64;
    long row0 = row0blk + wave * 16;

    {
        const uint4* s = (const uint4*)WtF;
        uint4* d = (uint4*)Bs;
        for (int i = tid; i < 2048; i += 256) d[i] = s[i];
    }

    half8 af[4];
    {
        long ar = row0 + m16; if (ar >= M) ar = M - 1;
        const float* Ap = &A[ar * DP + quad * 8];
#pragma unroll
        for (int k0 = 0; k0 < 4; k0++) {
            float4 v0 = *(const float4*)(Ap + k0 * 32);
            float4 v1 = *(const float4*)(Ap + k0 * 32 + 4);
            half8 o;
            o[0] = (_Float16)v0.x; o[1] = (_Float16)v0.y;
            o[2] = (_Float16)v0.z; o[3] = (_Float16)v0.w;
            o[4] = (_Float16)v1.x; o[5] = (_Float16)v1.y;
            o[6] = (_Float16)v1.z; o[7] = (_Float16)v1.w;
            af[k0] = o;
        }
    }
    __syncthreads();

    floatx4 acc[8];
#pragma unroll
    for (int t = 0; t < 8; t++) acc[t] = (floatx4){0.f, 0.f, 0.f, 0.f};

#pragma unroll
    for (int c = 0; c < 32; c++) {
        half8 bf = *(const half8*)&Bs[(c * 64 + lane) * 8];
        acc[c >> 2] = __builtin_amdgcn_mfma_f32_16x16x32_f16(af[c & 3], bf, acc[c >> 2], 0, 0, 0);
    }
    __syncthreads();

    int lrow0 = wave * 16 + quad * 4;
#pragma unroll
    for (int t = 0; t < 8; t++)
#pragma unroll
        for (int r = 0; r < 4; r++)
            Ct[(lrow0 + r) * 132 + t * 16 + m16] = acc[t][r];
    __syncthreads();

    for (int idx = tid; idx < 64 * 32; idx += 256) {
        int lr = idx >> 5, c4 = idx & 31;
        long grow = row0blk + lr;
        int col = c4 * 4;
        if (grow >= M || col >= NCOLS) continue;
        float4 v = *(const float4*)&Ct[lr * 132 + col];
        float rs = rowscale[grow];
        v.x *= rs; v.y *= rs; v.z *= rs; v.w *= rs;
        __half2 p01 = __floats2half2_rn(v.x, v.y);
        __half2 p23 = __floats2half2_rn(v.z, v.w);
        uint2 u;
        u.x = *(unsigned int*)&p01;
        u.y = *(unsigned int*)&p23;
        *(uint2*)&Ch[((size_t)(col >> 4) * M + grow) * 16 + (col & 15)] = u;
    }
}

// ---------------- MFMA matmul, fp16 A (sliced): C = (A@W) * rowscale -> fp16 sliced ----------------
__global__ __launch_bounds__(256) void matmul_a16_kernel(
        const __half* __restrict__ A, const _Float16* __restrict__ WtF,
        const float* __restrict__ rowscale, __half* __restrict__ Ch, int M) {
    __shared__ char smraw[64 * 132 * 4];
    _Float16* Bs = (_Float16*)smraw;
    float* Ct = (float*)smraw;
    int tid = threadIdx.x;
    int wave = tid >> 6;
    int lane = tid & 63;
    int m16 = lane & 15;
    int quad = lane >> 4;
    long row0blk = (long)blockIdx.x * 64;
    long row0 = row0blk + wave * 16;

    {
        const uint4* s = (const uint4*)WtF;
        uint4* d = (uint4*)Bs;
        for (int i = tid; i < 2048; i += 256) d[i] = s[i];
    }

    half8 af[4];
    {
        long ar = row0 + m16; if (ar >= M) ar = M - 1;
#pragma unroll
        for (int k0 = 0; k0 < 4; k0++) {
            int c0 = quad * 8 + k0 * 32;
            if (c0 < NCOLS) {
                af[k0] = *(const half8*)&((const _Float16*)A)[((size_t)(c0 >> 4) * M + ar) * 16 + (c0 & 15)];
            } else {
                half8 z;
#pragma unroll
                for (int jj = 0; jj < 8; jj++) z[jj] = (_Float16)0.f;
                af[k0] = z;
            }
        }
    }
    __syncthreads();

    floatx4 acc[8];
#pragma unroll
    for (int t = 0; t < 8; t++) acc[t] = (floatx4){0.f, 0.f, 0.f, 0.f};

#pragma unroll
    for (int c = 0; c < 32; c++) {
        half8 bf = *(const half8*)&Bs[(c * 64 + lane) * 8];
        acc[c >> 2] = __builtin_amdgcn_mfma_f32_16x16x32_f16(af[c & 3], bf, acc[c >> 2], 0, 0, 0);
    }
    __syncthreads();

    int lrow0 = wave * 16 + quad * 4;
#pragma unroll
    for (int t = 0; t < 8; t++)
#pragma unroll
        for (int r = 0; r < 4; r++)
            Ct[(lrow0 + r) * 132 + t * 16 + m16] = acc[t][r];
    __syncthreads();

    for (int idx = tid; idx < 64 * 32; idx += 256) {
        int lr = idx >> 5, c4 = idx & 31;
        long grow = row0blk + lr;
        int col = c4 * 4;
        if (grow >= M || col >= NCOLS) continue;
        float4 v = *(const float4*)&Ct[lr * 132 + col];
        float rs = rowscale[grow];
        v.x *= rs; v.y *= rs; v.z *= rs; v.w *= rs;
        __half2 p01 = __floats2half2_rn(v.x, v.y);
        __half2 p23 = __floats2half2_rn(v.z, v.w);
        uint2 u;
        u.x = *(unsigned int*)&p01;
        u.y = *(unsigned int*)&p23;
        *(uint2*)&Ch[((size_t)(col >> 4) * M + grow) * 16 + (col & 15)] = u;
    }
}

// ---------------- dual MFMA matmul with fused BN on A (sliced in/out) ----------------
__global__ __launch_bounds__(256) void matmul_dual_kernel(
        const __half* __restrict__ A, const _Float16* __restrict__ WtF3,
        const _Float16* __restrict__ WtF4, const float* __restrict__ ba,
        const float* __restrict__ rowscale,
        const float* __restrict__ bnscale, const float* __restrict__ bnshift,
        __half* __restrict__ Ch1, __half* __restrict__ ChR, int M, int Kout) {
    __shared__ char smraw[64 * 132 * 4];
    _Float16* Bs = (_Float16*)smraw;
    float* Ct = (float*)smraw;
    int tid = threadIdx.x;
    int wave = tid >> 6;
    int lane = tid & 63;
    int m16 = lane & 15;
    int quad = lane >> 4;
    long row0blk = (long)blockIdx.x * 64;
    long row0 = row0blk + wave * 16;

    half8 af[4];
    {
        long ar = row0 + m16; if (ar >= M) ar = M - 1;
#pragma unroll
        for (int k0 = 0; k0 < 4; k0++) {
            int c0 = quad * 8 + k0 * 32;
            half8 o;
            if (c0 < NCOLS) {
                half8 h = *(const half8*)&((const _Float16*)A)[((size_t)(c0 >> 4) * M + ar) * 16 + (c0 & 15)];
                float4 sc0 = *(const float4*)&bnscale[c0];
                float4 sc1 = *(const float4*)&bnscale[c0 + 4];
                float4 sh0 = *(const float4*)&bnshift[c0];
                float4 sh1 = *(const float4*)&bnshift[c0 + 4];
                o[0] = (_Float16)((float)h[0] * sc0.x + sh0.x);
                o[1] = (_Float16)((float)h[1] * sc0.y + sh0.y);
                o[2] = (_Float16)((float)h[2] * sc0.z + sh0.z);
                o[3] = (_Float16)((float)h[3] * sc0.w + sh0.w);
                o[4] = (_Float16)((float)h[4] * sc1.x + sh1.x);
                o[5] = (_Float16)((float)h[5] * sc1.y + sh1.y);
                o[6] = (_Float16)((float)h[6] * sc1.z + sh1.z);
                o[7] = (_Float16)((float)h[7] * sc1.w + sh1.w);
            } else {
#pragma unroll
                for (int jj = 0; jj < 8; jj++) o[jj] = (_Float16)0.f;
            }
            af[k0] = o;
        }
    }

    floatx4 acc3[8], acc4[8];
#pragma unroll
    for (int t = 0; t < 8; t++) {
        acc3[t] = (floatx4){0.f, 0.f, 0.f, 0.f};
        acc4[t] = (floatx4){0.f, 0.f, 0.f, 0.f};
    }

    // --- W3 pass ---
    {
        const uint4* s = (const uint4*)WtF3;
        uint4* d = (uint4*)Bs;
        for (int i = tid; i < 2048; i += 256) d[i] = s[i];
    }
    __syncthreads();
#pragma unroll
    for (int c = 0; c < 32; c++) {
        half8 bf = *(const half8*)&Bs[(c * 64 + lane) * 8];
        acc3[c >> 2] = __builtin_amdgcn_mfma_f32_16x16x32_f16(af[c & 3], bf, acc3[c >> 2], 0, 0, 0);
    }
    __syncthreads();

    // --- W4 pass ---
    {
        const uint4* s = (const uint4*)WtF4;
        uint4* d = (uint4*)Bs;
        for (int i = tid; i < 2048; i += 256) d[i] = s[i];
    }
    __syncthreads();
#pragma unroll
    for (int c = 0; c < 32; c++) {
        half8 bf = *(const half8*)&Bs[(c * 64 + lane) * 8];
        acc4[c >> 2] = __builtin_amdgcn_mfma_f32_16x16x32_f16(af[c & 3], bf, acc4[c >> 2], 0, 0, 0);
    }
    __syncthreads();

    int lrow0 = wave * 16 + quad * 4;

    // --- P1 epilogue: rowscale ---
#pragma unroll
    for (int t = 0; t < 8; t++)
#pragma unroll
        for (int r = 0; r < 4; r++)
            Ct[(lrow0 + r) * 132 + t * 16 + m16] = acc3[t][r];
    __syncthreads();
    for (int idx = tid; idx < 64 * 32; idx += 256) {
        int lr = idx >> 5, c4 = idx & 31;
        long grow = row0blk + lr;
        int col = c4 * 4;
        if (grow >= M || col >= NCOLS) continue;
        float4 v = *(const float4*)&Ct[lr * 132 + col];
        float rs = rowscale[grow];
        v.x *= rs; v.y *= rs; v.z *= rs; v.w *= rs;
        __half2 p01 = __floats2half2_rn(v.x, v.y);
        __half2 p23 = __floats2half2_rn(v.z, v.w);
        uint2 u;
        u.x = *(unsigned int*)&p01;
        u.y = *(unsigned int*)&p23;
        *(uint2*)&Ch1[((size_t)(col >> 4) * M + grow) * 16 + (col & 15)] = u;
    }
    __syncthreads();

    // --- R epilogue: +ba ---
#pragma unroll
    for (int t = 0; t < 8; t++)
#pragma unroll
        for (int r = 0; r < 4; r++)
            Ct[(lrow0 + r) * 132 + t * 16 + m16] = acc4[t][r];
    __syncthreads();
    for (int idx = tid; idx < 64 * 32; idx += 256) {
        int lr = idx >> 5, c4 = idx & 31;
        long grow = row0blk + lr;
        int col = c4 * 4;
        if (grow >= M || col >= NCOLS) continue;
        float4 v = *(const float4*)&Ct[lr * 132 + col];
        if (col < Kout) {
            float4 bb = *(const float4*)&ba[col];
            v.x += bb.x; v.y += bb.y; v.z += bb.z; v.w += bb.w;
        }
        __half2 p01 = __floats2half2_rn(v.x, v.y);
        __half2 p23 = __floats2half2_rn(v.z, v.w);
        uint2 u;
        u.x = *(unsigned int*)&p01;
        u.y = *(unsigned int*)&p23;
        *(uint2*)&ChR[((size_t)(col >> 4) * M + grow) * 16 + (col & 15)] = u;
    }
}

// ---------------- BN stats over h2 (sliced) ----------------
__global__ __launch_bounds__(512) void bnstats_kernel(const __half* __restrict__ h,
                                                      float* __restrict__ bnsum,
                                                      float* __restrict__ bnsq, int n) {
    __shared__ float2 sred[512], qred[512];
    int tid = threadIdx.x;
    int col2 = tid & 63;
    int rgrp = tid >> 6;                      // 8 row groups
    float2 s = make_float2(0.f, 0.f), qv = make_float2(0.f, 0.f);
    if (col2 < 52) {
        size_t sbase = (size_t)(col2 >> 3) * n;
        int coff = (col2 * 2) & 15;
        for (int r = blockIdx.x * 8 + rgrp; r < n; r += gridDim.x * 8) {
            __half2 hv = *(const __half2*)&h[(sbase + r) * 16 + coff];
            float2 f = __half22float2(hv);
            s.x += f.x; s.y += f.y;
            qv.x += f.x * f.x; qv.y += f.y * f.y;
        }
    }
    sred[tid] = s; qred[tid] = qv;
    __syncthreads();
    if (tid < 52) {
        float2 ts = make_float2(0.f, 0.f), tq = make_float2(0.f, 0.f);
#pragma unroll
        for (int gg = 0; gg < 8; gg++) {
            float2 v = sred[gg * 64 + tid]; ts.x += v.x; ts.y += v.y;
            v = qred[gg * 64 + tid]; tq.x += v.x; tq.y += v.y;
        }
        atomicAdd(&bnsum[tid * 2], ts.x);
        atomicAdd(&bnsum[tid * 2 + 1], ts.y);
        atomicAdd(&bnsq[tid * 2], tq.x);
        atomicAdd(&bnsq[tid * 2 + 1], tq.y);
    }
}

// ---------------- bn prep ----------------
__global__ void bn_prep_kernel(const float* __restrict__ sum, const float* __restrict__ sq,
                               const float* __restrict__ gamma, const float* __restrict__ beta,
                               float* __restrict__ scale, float* __restrict__ shift, int n) {
    int c = threadIdx.x;
    float sc = 0.f, sh = 0.f;
    if (c < DIM) {
        float inv_n = 1.0f / (float)n;
        float mu = sum[c] * inv_n;
        float var = sq[c] * inv_n - mu * mu;
        float rs = rsqrtf(var + EPSBN);
        sc = rs * gamma[c];
        sh = beta[c] - mu * sc;
    }
    scale[c] = sc;
    shift[c] = sh;
}

// ---------------- graph boundaries ----------------
__global__ void gbounds_kernel(const int* __restrict__ batch, int* __restrict__ gstart, int n) {
    int g = threadIdx.x;
    int lo = 0, hi = n;
    while (lo < hi) {
        int mid = (lo + hi) >> 1;
        if (batch[mid] < g) lo = mid + 1; else hi = mid;
    }
    gstart[g] = lo;
    if (g == 0) gstart[NGRAPH] = n;
}

// ---------------- global add pool (fp16 input, sliced) ----------------
__global__ __launch_bounds__(512) void pool_kernel(const __half* __restrict__ a,
                                                   const int* __restrict__ gstart,
                                                   float* __restrict__ g, int n) {
    __shared__ float2 red[512];
    int b = blockIdx.x, tid = threadIdx.x;
    int col2 = tid & 63;
    int rgrp = tid >> 6;
    int lo = gstart[b], hi = gstart[b + 1];
    float2 s = make_float2(0.f, 0.f);
    if (col2 < 52) {
        size_t sbase = (size_t)(col2 >> 3) * n;
        int coff = (col2 * 2) & 15;
        for (int r = lo + rgrp; r < hi; r += 8) {
            __half2 h = *(const __half2*)&a[(sbase + r) * 16 + coff];
            float2 f = __half22float2(h);
            s.x += f.x; s.y += f.y;
        }
    }
    red[tid] = s;
    __syncthreads();
    if (tid < 52) {
        float2 t = make_float2(0.f, 0.f);
#pragma unroll
        for (int gg = 0; gg < 8; gg++) {
            float2 v = red[gg * 64 + tid];
            t.x += v.x; t.y += v.y;
        }
        *(float2*)&g[b * DP + tid * 2] = t;
    }
}

// ---------------- fused MLP head ----------------
__global__ __launch_bounds__(256) void mlp_kernel(
        const float* __restrict__ g,
        const float* __restrict__ Wf1, const float* __restrict__ bf1,
        const float* __restrict__ Wf2, const float* __restrict__ bf2,
        const float* __restrict__ Wf3, const float* __restrict__ bf3,
        const float* __restrict__ Wf4, const float* __restrict__ bf4,
        float* __restrict__ out) {
    __shared__ float a0[100], a1[200], a2[300], a3[200], red[256];
    int b = blockIdx.x, tid = threadIdx.x;
    if (tid < 100) a0[tid] = g[b * DP + tid];
    __syncthreads();
    for (int c = tid; c < 200; c += 256) {
        float s = bf1[c];
        for (int k = 0; k < 100; k++) s += a0[k] * Wf1[k * 200 + c];
        a1[c] = fmaxf(s, 0.f);
    }
    __syncthreads();
    for (int c = tid; c < 300; c += 256) {
        float s = bf2[c];
        for (int k = 0; k < 200; k++) s += a1[k] * Wf2[k * 300 + c];
        a2[c] = fmaxf(s, 0.f);
    }
    __syncthreads();
    for (int c = tid; c < 200; c += 256) {
        float s = bf3[c];
        for (int k = 0; k < 300; k++) s += a2[k] * Wf3[k * 200 + c];
        a3[c] = fmaxf(s, 0.f);
    }
    __syncthreads();
    red[tid] = (tid < 200) ? a3[tid] * Wf4[tid] : 0.f;
    __syncthreads();
    for (int o = 128; o > 0; o >>= 1) {
        if (tid < o) red[tid] += red[tid + o];
        __syncthreads();
    }
    if (tid == 0) out[b] = red[0] + bf4[0];
}

extern "C" void kernel_launch(void* const* d_in, const int* in_sizes, int n_in,
                              void* d_out, int out_size, void* d_ws, size_t ws_size,
                              hipStream_t stream) {
    const float* x      = (const float*)d_in[0];
    const int*   src    = (const int*)d_in[1];
    const int*   dst    = (const int*)d_in[2];
    const int*   batch  = (const int*)d_in[3];
    const float* W1     = (const float*)d_in[4];
    const float* b1     = (const float*)d_in[5];
    const float* W2     = (const float*)d_in[6];
    const float* b2     = (const float*)d_in[7];
    const float* gamma  = (const float*)d_in[8];
    const float* beta   = (const float*)d_in[9];
    const float* Wa_init= (const float*)d_in[10];
    const float* Wa_root= (const float*)d_in[11];
    const float* ba     = (const float*)d_in[12];
    const float* Wf1    = (const float*)d_in[13];
    const float* bf1    = (const float*)d_in[14];
    const float* Wf2    = (const float*)d_in[15];
    const float* bf2    = (const float*)d_in[16];
    const float* Wf3    = (const float*)d_in[17];
    const float* bf3    = (const float*)d_in[18];
    const float* Wf4    = (const float*)d_in[19];
    const float* bf4    = (const float*)d_in[20];
    float* out = (float*)d_out;

    const int n = NNODES;
    const int e = NEDGES;

    char* ws = (char*)d_ws;
    auto carve = [&](size_t bytes) -> void* {
        void* p = (void*)ws;
        ws += (bytes + 255) & ~(size_t)255;
        return p;
    };
    const size_t fbytes = (size_t)n * SLICES * 16 * 2;   // sliced feature buffer
    __half* buf0    = (__half*)carve(fbytes);   // Y1 / Y2 / P1
    __half* buf1    = (__half*)carve(fbytes);   // H1 / H2
    __half* bufR    = (__half*)carve(fbytes);   // R
    __half* bufC    = (__half*)carve(fbytes);   // ARMA out
    _Float16* Wt1   = (_Float16*)carve((size_t)DP * DP * 2);
    _Float16* Wt2   = (_Float16*)carve((size_t)DP * DP * 2);
    _Float16* Wt3   = (_Float16*)carve((size_t)DP * DP * 2);
    _Float16* Wt4   = (_Float16*)carve((size_t)DP * DP * 2);
    int*    off     = (int*)carve((size_t)(n + 1) * 4);
    int*    btotal  = (int*)carve((size_t)NBUK * 4);
    int*    bbase   = (int*)carve((size_t)(NBUK + 1) * 4);
    int*    bcursor = (int*)carve((size_t)NBUK * 4);
    int*    ssorted = (int*)carve((size_t)e * 4);
    int2*   gpairs  = (int2*)carve((size_t)e * 8);
    float*  dinv_sl = (float*)carve((size_t)n * 4);
    float*  dinv_nsl= (float*)carve((size_t)n * 4);
    float*  bnsum   = (float*)carve(DP * 4);
    float*  bnsq    = (float*)carve(DP * 4);
    float*  bnscale = (float*)carve(DP * 4);
    float*  bnshift = (float*)carve(DP * 4);
    float*  b1p     = (float*)carve(DP * 4);
    float*  b2p     = (float*)carve(DP * 4);
    int*    qcur    = (int*)carve(3 * 8 * 4);            // 3 prop work queues
    int*    gstart  = (int*)carve((size_t)(NGRAPH + 1) * 4);
    float*  gpool   = (float*)carve((size_t)NGRAPH * DP * 4);

    const int nchunk = (e + BINCH - 1) / BINCH;
    const int nch = (n + CHNODES - 1) / CHNODES;         // prop chunks per slice
    const int prop_grid = 8 * nch;                        // ~1/8 of blocks per XCD
    const int mm_blocks = (n + 63) / 64;

    // ---- pack weights + pad biases ----
    packW4_kernel<<<256, 256, 0, stream>>>(W1, W2, Wa_init, Wa_root, Wt1, Wt2, Wt3, Wt4);
    padb_kernel<<<1, 128, 0, stream>>>(b1, b2, b1p, b2p);

    // ---- build CSR by dst ----
    hipMemsetAsync(btotal, 0, (size_t)NBUK * 4, stream);
    hipMemsetAsync(bnsum, 0, DP * 4, stream);
    hipMemsetAsync(bnsq, 0, DP * 4, stream);
    hipMemsetAsync(qcur, 0, 3 * 8 * 4, stream);
    bin_count_kernel<<<nchunk, 256, 0, stream>>>(dst, btotal, e);
    bucket_scan_kernel<<<1, 512, 0, stream>>>(btotal, bbase, bcursor, e);
    bin_kernel<<<nchunk, 256, 0, stream>>>(src, dst, bcursor, gpairs, e);
    bucket_build_kernel<<<NBUK, 256, 0, stream>>>(gpairs, bbase, off, ssorted, dinv_sl, dinv_nsl, n, e);
    gbounds_kernel<<<1, 512, 0, stream>>>(batch, gstart, n);

    // ---- SGConv 1 (matmul first: prop(x)@W1 == prop(x@W1)) ----
    matmul_a32_kernel<<<mm_blocks, 256, 0, stream>>>(x, Wt1, dinv_sl, buf0, n);
    prop_slice_kernel<<<prop_grid, 256, 0, stream>>>(buf0, ssorted, off, dinv_sl, b1p, buf1, qcur, n, nch);

    // ---- SGConv 2 ----
    matmul_a16_kernel<<<mm_blocks, 256, 0, stream>>>(buf1, Wt2, dinv_sl, buf0, n);
    prop_slice_kernel<<<prop_grid, 256, 0, stream>>>(buf0, ssorted, off, dinv_sl, b2p, buf1, qcur + 8, n, nch);

    // ---- BatchNorm stats + params ----
    bnstats_kernel<<<512, 512, 0, stream>>>(buf1, bnsum, bnsq, n);
    bn_prep_kernel<<<1, 128, 0, stream>>>(bnsum, bnsq, gamma, beta, bnscale, bnshift, n);

    // ---- ARMAConv: dual matmul with fused BN, then prop with fused add+relu ----
    matmul_dual_kernel<<<mm_blocks, 256, 0, stream>>>(buf1, Wt3, Wt4, ba, dinv_nsl, bnscale, bnshift, buf0, bufR, n, DIM);
    prop_arma_slice_kernel<<<prop_grid, 256, 0, stream>>>(buf0, ssorted, off, dinv_nsl, bufR, bufC, qcur + 16, n, nch);

    // ---- global add pool ----
    pool_kernel<<<NGRAPH, 512, 0, stream>>>(bufC, gstart, gpool, n);

    // ---- MLP head ----
    mlp_kernel<<<NGRAPH, 256, 0, stream>>>(gpool, Wf1, bf1, Wf2, bf2, Wf3, bf3, Wf4, bf4, out);
}

// Round 4
// 532.130 us; speedup vs baseline: 7.1236x; 7.1236x over previous
//
#include <hip/hip_runtime.h>
#include <hip/hip_fp16.h>

#define NNODES 100000
#define NEDGES 1600000
#define NGRAPH 512
#define DIM    100
#define DP     128
#define EPSBN  1e-5f
#define NBUK   ((NNODES + 255) >> 8)
#define BINCH  8192

typedef _Float16 half8 __attribute__((ext_vector_type(8)));
typedef float floatx4 __attribute__((ext_vector_type(4)));

// ---------------- pass 0: per-chunk bucket counts ----------------
__global__ __launch_bounds__(256) void bin_count_kernel(const int* __restrict__ dst,
                                                        int* __restrict__ btotal, int e) {
    __shared__ int lc[NBUK];
    int tid = threadIdx.x;
    int base = blockIdx.x * BINCH;
    int m = e - base; if (m > BINCH) m = BINCH;
    for (int b = tid; b < NBUK; b += 256) lc[b] = 0;
    __syncthreads();
    for (int j = tid; j < m; j += 256)
        atomicAdd(&lc[dst[base + j] >> 8], 1);
    __syncthreads();
    for (int b = tid; b < NBUK; b += 256)
        if (lc[b]) atomicAdd(&btotal[b], lc[b]);
}

// ---------------- bucket exclusive scan ----------------
__global__ void bucket_scan_kernel(const int* __restrict__ btotal, int* __restrict__ bbase,
                                   int* __restrict__ bcursor, int e) {
    __shared__ int s[512];
    int tid = threadIdx.x;
    int v = (tid < NBUK) ? btotal[tid] : 0;
    s[tid] = v; __syncthreads();
    for (int o = 1; o < 512; o <<= 1) {
        int t = (tid >= o) ? s[tid - o] : 0;
        __syncthreads();
        s[tid] += t;
        __syncthreads();
    }
    if (tid < NBUK) {
        int base = s[tid] - v;
        bbase[tid] = base;
        bcursor[tid] = base;
    }
    if (tid == 0) bbase[NBUK] = e;
}

// ---------------- pass 1: bin pairs bucket-major ----------------
__global__ __launch_bounds__(256) void bin_kernel(
        const int* __restrict__ src, const int* __restrict__ dst,
        int* __restrict__ bcursor, int2* __restrict__ gpairs, int e) {
    __shared__ int2 lpairs[BINCH];
    __shared__ int lcount[NBUK], lstart[NBUK], lcur[NBUK], gbase[NBUK];
    int tid = threadIdx.x;
    int base = blockIdx.x * BINCH;
    int m = e - base; if (m > BINCH) m = BINCH;

    for (int b = tid; b < NBUK; b += 256) lcount[b] = 0;
    __syncthreads();
    for (int j = tid; j < m; j += 256)
        atomicAdd(&lcount[dst[base + j] >> 8], 1);
    __syncthreads();
    if (tid == 0) {
        int acc = 0;
        for (int b = 0; b < NBUK; b++) {
            lstart[b] = acc;
            lcur[b] = acc;
            acc += lcount[b];
        }
    }
    __syncthreads();
    for (int b = tid; b < NBUK; b += 256)
        gbase[b] = atomicAdd(&bcursor[b], lcount[b]);
    for (int j = tid; j < m; j += 256) {
        int s = src[base + j], d = dst[base + j];
        int p = atomicAdd(&lcur[d >> 8], 1);
        lpairs[p] = make_int2(s, d);
    }
    __syncthreads();
    for (int j = tid; j < m; j += 256) {
        int2 pr = lpairs[j];
        int b = pr.y >> 8;
        gpairs[gbase[b] + (j - lstart[b])] = pr;
    }
}

// ---------------- pass 2: fused per-bucket build ----------------
__global__ __launch_bounds__(256) void bucket_build_kernel(
        const int2* __restrict__ gpairs, const int* __restrict__ bbase,
        int* __restrict__ off, int* __restrict__ ssorted,
        float* __restrict__ dsl, float* __restrict__ dnsl, int n, int e) {
    __shared__ int cnt[256];
    __shared__ int sc[256];
    int b = blockIdx.x, tid = threadIdx.x;
    int node0 = b << 8;
    int e0 = bbase[b], e1 = bbase[b + 1];

    cnt[tid] = 0;
    __syncthreads();
    for (int j = e0 + tid; j < e1; j += 256)
        atomicAdd(&cnt[gpairs[j].y & 255], 1);
    __syncthreads();

    int c = cnt[tid];
    sc[tid] = c; __syncthreads();
    for (int o = 1; o < 256; o <<= 1) {
        int t = (tid >= o) ? sc[tid - o] : 0;
        __syncthreads();
        sc[tid] += t;
        __syncthreads();
    }
    int excl = sc[tid] - c;

    int node = node0 + tid;
    if (node < n) {
        off[node] = e0 + excl;
        float cf = (float)c;
        dsl[node] = rsqrtf(cf + 1.0f);
        dnsl[node] = (c > 0) ? rsqrtf(cf) : 0.0f;
    }
    if (b == NBUK - 1 && tid == 0) off[n] = e;

    __syncthreads();
    cnt[tid] = e0 + excl;
    __syncthreads();
    for (int j = e0 + tid; j < e1; j += 256) {
        int2 pr = gpairs[j];
        int p = atomicAdd(&cnt[pr.y & 255], 1);
        ssorted[p] = pr.x;
    }
}

// ---------------- pack all 4 W into MFMA fragment order (one launch) ----------------
__global__ void packW4_kernel(const float* __restrict__ W1, const float* __restrict__ W2,
                              const float* __restrict__ W3, const float* __restrict__ W4,
                              _Float16* __restrict__ Wt1, _Float16* __restrict__ Wt2,
                              _Float16* __restrict__ Wt3, _Float16* __restrict__ Wt4) {
    int which = blockIdx.x >> 6;          // 64 blocks per weight
    int idx = (blockIdx.x & 63) * 256 + threadIdx.x;
    const float* W = (which == 0) ? W1 : (which == 1) ? W2 : (which == 2) ? W3 : W4;
    _Float16* Wt  = (which == 0) ? Wt1 : (which == 1) ? Wt2 : (which == 2) ? Wt3 : Wt4;
    int K = (which == 0) ? 128 : DIM;
    int j = idx & 7;
    int l = (idx >> 3) & 63;
    int c = idx >> 9;
    int t = c >> 2, k0 = c & 3;
    int nn = t * 16 + (l & 15);
    int k = k0 * 32 + (l >> 4) * 8 + j;
    float v = (k < K && nn < DIM) ? W[k * DIM + nn] : 0.f;
    Wt[idx] = (_Float16)v;
}

// ---------------- pad biases to 128 ----------------
__global__ void padb_kernel(const float* __restrict__ b1, const float* __restrict__ b2,
                            float* __restrict__ b1p, float* __restrict__ b2p) {
    int c = threadIdx.x;
    b1p[c] = (c < DIM) ? b1[c] : 0.f;
    b2p[c] = (c < DIM) ? b2[c] : 0.f;
}

// ---------------- propagation (self-loop) : out = relu(dinv*sum + bias), DP stride ----------------
__global__ __launch_bounds__(256) void prop_kernel(
        const __half* __restrict__ pre, const int* __restrict__ ssorted,
        const int* __restrict__ off, const float* __restrict__ dinv,
        const float* __restrict__ bias, __half* __restrict__ outH, int n) {
    int wave = (blockIdx.x * blockDim.x + threadIdx.x) >> 6;
    int lane = threadIdx.x & 63;
    if (wave >= n) return;
    int e0 = off[wave], e1 = off[wave + 1];
    int deg = e1 - e0;
    int g = lane >> 4;
    int q = lane & 15;

    float acc[8];
#pragma unroll
    for (int i = 0; i < 8; i++) acc[i] = 0.f;

    auto addu = [&](uint4 u) {
        float2 f;
        f = __half22float2(*(__half2*)&u.x); acc[0] += f.x; acc[1] += f.y;
        f = __half22float2(*(__half2*)&u.y); acc[2] += f.x; acc[3] += f.y;
        f = __half22float2(*(__half2*)&u.z); acc[4] += f.x; acc[5] += f.y;
        f = __half22float2(*(__half2*)&u.w); acc[6] += f.x; acc[7] += f.y;
    };
    auto rowptr = [&](int s) -> const uint4* {
        return (const uint4*)&pre[(long)s * DP + q * 8];
    };

    for (int base = 0; base < deg; base += 64) {
        int m = deg - base; if (m > 64) m = 64;
        int sidx = (lane < m) ? ssorted[e0 + base + lane] : 0;
        int j = 0;
        for (; j + 16 <= m; j += 16) {
            int s0 = __shfl(sidx, j + g);
            int s1 = __shfl(sidx, j + 4 + g);
            int s2 = __shfl(sidx, j + 8 + g);
            int s3 = __shfl(sidx, j + 12 + g);
            uint4 u0 = *rowptr(s0);
            uint4 u1 = *rowptr(s1);
            uint4 u2 = *rowptr(s2);
            uint4 u3 = *rowptr(s3);
            addu(u0); addu(u1); addu(u2); addu(u3);
        }
        for (; j + 4 <= m; j += 4) {
            int s = __shfl(sidx, j + g);
            addu(*rowptr(s));
        }
        if (j < m) {
            int r = m - j;
            int s = __shfl(sidx, (g < r) ? j + g : j);
            if (g < r) addu(*rowptr(s));
        }
    }

#pragma unroll
    for (int i = 0; i < 8; i++) {
        acc[i] += __shfl_xor(acc[i], 16);
        acc[i] += __shfl_xor(acc[i], 32);
    }

    if (g == 0) {
        float dn = dinv[wave];
        addu(*rowptr(wave));                // self-loop (pre already dsl-scaled)
        float4 b0 = *(const float4*)&bias[q * 8];
        float4 b1v = *(const float4*)&bias[q * 8 + 4];
        float o[8];
        o[0] = fmaxf(dn * acc[0] + b0.x, 0.f);
        o[1] = fmaxf(dn * acc[1] + b0.y, 0.f);
        o[2] = fmaxf(dn * acc[2] + b0.z, 0.f);
        o[3] = fmaxf(dn * acc[3] + b0.w, 0.f);
        o[4] = fmaxf(dn * acc[4] + b1v.x, 0.f);
        o[5] = fmaxf(dn * acc[5] + b1v.y, 0.f);
        o[6] = fmaxf(dn * acc[6] + b1v.z, 0.f);
        o[7] = fmaxf(dn * acc[7] + b1v.w, 0.f);
        __half2 p0 = __floats2half2_rn(o[0], o[1]);
        __half2 p1 = __floats2half2_rn(o[2], o[3]);
        __half2 p2 = __floats2half2_rn(o[4], o[5]);
        __half2 p3 = __floats2half2_rn(o[6], o[7]);
        uint4 u;
        u.x = *(unsigned int*)&p0;
        u.y = *(unsigned int*)&p1;
        u.z = *(unsigned int*)&p2;
        u.w = *(unsigned int*)&p3;
        *(uint4*)&outH[(long)wave * DP + q * 8] = u;
    }
}

// ---------------- ARMA prop: out = relu(dinv*sum + R), no self-loop, DP stride ----------------
__global__ __launch_bounds__(256) void prop_arma_kernel(
        const __half* __restrict__ pre, const int* __restrict__ ssorted,
        const int* __restrict__ off, const float* __restrict__ dinv,
        const __half* __restrict__ R, __half* __restrict__ outH, int n) {
    int wave = (blockIdx.x * blockDim.x + threadIdx.x) >> 6;
    int lane = threadIdx.x & 63;
    if (wave >= n) return;
    int e0 = off[wave], e1 = off[wave + 1];
    int deg = e1 - e0;
    int g = lane >> 4;
    int q = lane & 15;

    float acc[8];
#pragma unroll
    for (int i = 0; i < 8; i++) acc[i] = 0.f;

    auto addu = [&](uint4 u) {
        float2 f;
        f = __half22float2(*(__half2*)&u.x); acc[0] += f.x; acc[1] += f.y;
        f = __half22float2(*(__half2*)&u.y); acc[2] += f.x; acc[3] += f.y;
        f = __half22float2(*(__half2*)&u.z); acc[4] += f.x; acc[5] += f.y;
        f = __half22float2(*(__half2*)&u.w); acc[6] += f.x; acc[7] += f.y;
    };
    auto rowptr = [&](int s) -> const uint4* {
        return (const uint4*)&pre[(long)s * DP + q * 8];
    };

    for (int base = 0; base < deg; base += 64) {
        int m = deg - base; if (m > 64) m = 64;
        int sidx = (lane < m) ? ssorted[e0 + base + lane] : 0;
        int j = 0;
        for (; j + 16 <= m; j += 16) {
            int s0 = __shfl(sidx, j + g);
            int s1 = __shfl(sidx, j + 4 + g);
            int s2 = __shfl(sidx, j + 8 + g);
            int s3 = __shfl(sidx, j + 12 + g);
            uint4 u0 = *rowptr(s0);
            uint4 u1 = *rowptr(s1);
            uint4 u2 = *rowptr(s2);
            uint4 u3 = *rowptr(s3);
            addu(u0); addu(u1); addu(u2); addu(u3);
        }
        for (; j + 4 <= m; j += 4) {
            int s = __shfl(sidx, j + g);
            addu(*rowptr(s));
        }
        if (j < m) {
            int r = m - j;
            int s = __shfl(sidx, (g < r) ? j + g : j);
            if (g < r) addu(*rowptr(s));
        }
    }

#pragma unroll
    for (int i = 0; i < 8; i++) {
        acc[i] += __shfl_xor(acc[i], 16);
        acc[i] += __shfl_xor(acc[i], 32);
    }

    if (g == 0) {
        float dn = dinv[wave];
        uint4 r4 = *(const uint4*)&R[(long)wave * DP + q * 8];
        float rr[8];
        float2 f;
        f = __half22float2(*(__half2*)&r4.x); rr[0] = f.x; rr[1] = f.y;
        f = __half22float2(*(__half2*)&r4.y); rr[2] = f.x; rr[3] = f.y;
        f = __half22float2(*(__half2*)&r4.z); rr[4] = f.x; rr[5] = f.y;
        f = __half22float2(*(__half2*)&r4.w); rr[6] = f.x; rr[7] = f.y;
        float o[8];
#pragma unroll
        for (int i = 0; i < 8; i++) o[i] = fmaxf(dn * acc[i] + rr[i], 0.f);
        __half2 p0 = __floats2half2_rn(o[0], o[1]);
        __half2 p1 = __floats2half2_rn(o[2], o[3]);
        __half2 p2 = __floats2half2_rn(o[4], o[5]);
        __half2 p3 = __floats2half2_rn(o[6], o[7]);
        uint4 u;
        u.x = *(unsigned int*)&p0;
        u.y = *(unsigned int*)&p1;
        u.z = *(unsigned int*)&p2;
        u.w = *(unsigned int*)&p3;
        *(uint4*)&outH[(long)wave * DP + q * 8] = u;
    }
}

// ---------------- MFMA matmul, fp32 A (x input): C = (A@W) * rowscale -> fp16 DP ----------------
__global__ __launch_bounds__(256) void matmul_a32_kernel(
        const float* __restrict__ A, const _Float16* __restrict__ WtF,
        const float* __restrict__ rowscale, __half* __restrict__ Ch, int M) {
    __shared__ char smraw[64 * 132 * 4];
    _Float16* Bs = (_Float16*)smraw;
    float* Ct = (float*)smraw;
    int tid = threadIdx.x;
    int wave = tid >> 6;
    int lane = tid & 63;
    int m16 = lane & 15;
    int quad = lane >> 4;
    long row0blk = (long)blockIdx.x * 64;
    long row0 = row0blk + wave * 16;

    {
        const uint4* s = (const uint4*)WtF;
        uint4* d = (uint4*)Bs;
        for (int i = tid; i < 2048; i += 256) d[i] = s[i];
    }

    half8 af[4];
    {
        long ar = row0 + m16; if (ar >= M) ar = M - 1;
        const float* Ap = &A[ar * DP + quad * 8];
#pragma unroll
        for (int k0 = 0; k0 < 4; k0++) {
            float4 v0 = *(const float4*)(Ap + k0 * 32);
            float4 v1 = *(const float4*)(Ap + k0 * 32 + 4);
            half8 o;
            o[0] = (_Float16)v0.x; o[1] = (_Float16)v0.y;
            o[2] = (_Float16)v0.z; o[3] = (_Float16)v0.w;
            o[4] = (_Float16)v1.x; o[5] = (_Float16)v1.y;
            o[6] = (_Float16)v1.z; o[7] = (_Float16)v1.w;
            af[k0] = o;
        }
    }
    __syncthreads();

    floatx4 acc[8];
#pragma unroll
    for (int t = 0; t < 8; t++) acc[t] = (floatx4){0.f, 0.f, 0.f, 0.f};

#pragma unroll
    for (int c = 0; c < 32; c++) {
        half8 bf = *(const half8*)&Bs[(c * 64 + lane) * 8];
        acc[c >> 2] = __builtin_amdgcn_mfma_f32_16x16x32_f16(af[c & 3], bf, acc[c >> 2], 0, 0, 0);
    }
    __syncthreads();

    int lrow0 = wave * 16 + quad * 4;
#pragma unroll
    for (int t = 0; t < 8; t++)
#pragma unroll
        for (int r = 0; r < 4; r++)
            Ct[(lrow0 + r) * 132 + t * 16 + m16] = acc[t][r];
    __syncthreads();

    for (int idx = tid; idx < 64 * 32; idx += 256) {
        int lr = idx >> 5, c4 = idx & 31;
        long grow = row0blk + lr;
        if (grow >= M) continue;
        int col = c4 * 4;
        float4 v = *(const float4*)&Ct[lr * 132 + col];
        float rs = rowscale[grow];
        v.x *= rs; v.y *= rs; v.z *= rs; v.w *= rs;
        __half2 p01 = __floats2half2_rn(v.x, v.y);
        __half2 p23 = __floats2half2_rn(v.z, v.w);
        uint2 u;
        u.x = *(unsigned int*)&p01;
        u.y = *(unsigned int*)&p23;
        *(uint2*)&Ch[grow * DP + col] = u;
    }
}

// ---------------- MFMA matmul, fp16 A (DP stride): C = (A@W) * rowscale -> fp16 DP ----------------
__global__ __launch_bounds__(256) void matmul_a16_kernel(
        const __half* __restrict__ A, const _Float16* __restrict__ WtF,
        const float* __restrict__ rowscale, __half* __restrict__ Ch, int M) {
    __shared__ char smraw[64 * 132 * 4];
    _Float16* Bs = (_Float16*)smraw;
    float* Ct = (float*)smraw;
    int tid = threadIdx.x;
    int wave = tid >> 6;
    int lane = tid & 63;
    int m16 = lane & 15;
    int quad = lane >> 4;
    long row0blk = (long)blockIdx.x * 64;
    long row0 = row0blk + wave * 16;

    {
        const uint4* s = (const uint4*)WtF;
        uint4* d = (uint4*)Bs;
        for (int i = tid; i < 2048; i += 256) d[i] = s[i];
    }

    half8 af[4];
    {
        long ar = row0 + m16; if (ar >= M) ar = M - 1;
        const _Float16* Ap = (const _Float16*)&A[ar * DP + quad * 8];
#pragma unroll
        for (int k0 = 0; k0 < 4; k0++)
            af[k0] = *(const half8*)(Ap + k0 * 32);
    }
    __syncthreads();

    floatx4 acc[8];
#pragma unroll
    for (int t = 0; t < 8; t++) acc[t] = (floatx4){0.f, 0.f, 0.f, 0.f};

#pragma unroll
    for (int c = 0; c < 32; c++) {
        half8 bf = *(const half8*)&Bs[(c * 64 + lane) * 8];
        acc[c >> 2] = __builtin_amdgcn_mfma_f32_16x16x32_f16(af[c & 3], bf, acc[c >> 2], 0, 0, 0);
    }
    __syncthreads();

    int lrow0 = wave * 16 + quad * 4;
#pragma unroll
    for (int t = 0; t < 8; t++)
#pragma unroll
        for (int r = 0; r < 4; r++)
            Ct[(lrow0 + r) * 132 + t * 16 + m16] = acc[t][r];
    __syncthreads();

    for (int idx = tid; idx < 64 * 32; idx += 256) {
        int lr = idx >> 5, c4 = idx & 31;
        long grow = row0blk + lr;
        if (grow >= M) continue;
        int col = c4 * 4;
        float4 v = *(const float4*)&Ct[lr * 132 + col];
        float rs = rowscale[grow];
        v.x *= rs; v.y *= rs; v.z *= rs; v.w *= rs;
        __half2 p01 = __floats2half2_rn(v.x, v.y);
        __half2 p23 = __floats2half2_rn(v.z, v.w);
        uint2 u;
        u.x = *(unsigned int*)&p01;
        u.y = *(unsigned int*)&p23;
        *(uint2*)&Ch[grow * DP + col] = u;
    }
}

// ---------------- dual MFMA matmul with fused BN on A: P1 = BN(A)@W3*rowscale ; R = BN(A)@W4 + ba ----------------
__global__ __launch_bounds__(256) void matmul_dual_kernel(
        const __half* __restrict__ A, const _Float16* __restrict__ WtF3,
        const _Float16* __restrict__ WtF4, const float* __restrict__ ba,
        const float* __restrict__ rowscale,
        const float* __restrict__ bnscale, const float* __restrict__ bnshift,
        __half* __restrict__ Ch1, __half* __restrict__ ChR, int M, int Kout) {
    __shared__ char smraw[64 * 132 * 4];
    _Float16* Bs = (_Float16*)smraw;
    float* Ct = (float*)smraw;
    int tid = threadIdx.x;
    int wave = tid >> 6;
    int lane = tid & 63;
    int m16 = lane & 15;
    int quad = lane >> 4;
    long row0blk = (long)blockIdx.x * 64;
    long row0 = row0blk + wave * 16;

    // A-frags with fused BatchNorm (per-column scale/shift; pad cols have scale=shift=0)
    half8 af[4];
    {
        long ar = row0 + m16; if (ar >= M) ar = M - 1;
        const _Float16* Ap = (const _Float16*)&A[ar * DP + quad * 8];
#pragma unroll
        for (int k0 = 0; k0 < 4; k0++) {
            half8 h = *(const half8*)(Ap + k0 * 32);
            int c0 = quad * 8 + k0 * 32;
            float4 sc0 = *(const float4*)&bnscale[c0];
            float4 sc1 = *(const float4*)&bnscale[c0 + 4];
            float4 sh0 = *(const float4*)&bnshift[c0];
            float4 sh1 = *(const float4*)&bnshift[c0 + 4];
            half8 o;
            o[0] = (_Float16)((float)h[0] * sc0.x + sh0.x);
            o[1] = (_Float16)((float)h[1] * sc0.y + sh0.y);
            o[2] = (_Float16)((float)h[2] * sc0.z + sh0.z);
            o[3] = (_Float16)((float)h[3] * sc0.w + sh0.w);
            o[4] = (_Float16)((float)h[4] * sc1.x + sh1.x);
            o[5] = (_Float16)((float)h[5] * sc1.y + sh1.y);
            o[6] = (_Float16)((float)h[6] * sc1.z + sh1.z);
            o[7] = (_Float16)((float)h[7] * sc1.w + sh1.w);
            af[k0] = o;
        }
    }

    floatx4 acc3[8], acc4[8];
#pragma unroll
    for (int t = 0; t < 8; t++) {
        acc3[t] = (floatx4){0.f, 0.f, 0.f, 0.f};
        acc4[t] = (floatx4){0.f, 0.f, 0.f, 0.f};
    }

    // --- W3 pass ---
    {
        const uint4* s = (const uint4*)WtF3;
        uint4* d = (uint4*)Bs;
        for (int i = tid; i < 2048; i += 256) d[i] = s[i];
    }
    __syncthreads();
#pragma unroll
    for (int c = 0; c < 32; c++) {
        half8 bf = *(const half8*)&Bs[(c * 64 + lane) * 8];
        acc3[c >> 2] = __builtin_amdgcn_mfma_f32_16x16x32_f16(af[c & 3], bf, acc3[c >> 2], 0, 0, 0);
    }
    __syncthreads();

    // --- W4 pass ---
    {
        const uint4* s = (const uint4*)WtF4;
        uint4* d = (uint4*)Bs;
        for (int i = tid; i < 2048; i += 256) d[i] = s[i];
    }
    __syncthreads();
#pragma unroll
    for (int c = 0; c < 32; c++) {
        half8 bf = *(const half8*)&Bs[(c * 64 + lane) * 8];
        acc4[c >> 2] = __builtin_amdgcn_mfma_f32_16x16x32_f16(af[c & 3], bf, acc4[c >> 2], 0, 0, 0);
    }
    __syncthreads();

    int lrow0 = wave * 16 + quad * 4;

    // --- P1 epilogue: rowscale only ---
#pragma unroll
    for (int t = 0; t < 8; t++)
#pragma unroll
        for (int r = 0; r < 4; r++)
            Ct[(lrow0 + r) * 132 + t * 16 + m16] = acc3[t][r];
    __syncthreads();
    for (int idx = tid; idx < 64 * 32; idx += 256) {
        int lr = idx >> 5, c4 = idx & 31;
        long grow = row0blk + lr;
        if (grow >= M) continue;
        int col = c4 * 4;
        float4 v = *(const float4*)&Ct[lr * 132 + col];
        float rs = rowscale[grow];
        v.x *= rs; v.y *= rs; v.z *= rs; v.w *= rs;
        __half2 p01 = __floats2half2_rn(v.x, v.y);
        __half2 p23 = __floats2half2_rn(v.z, v.w);
        uint2 u;
        u.x = *(unsigned int*)&p01;
        u.y = *(unsigned int*)&p23;
        *(uint2*)&Ch1[grow * DP + col] = u;
    }
    __syncthreads();

    // --- R epilogue: +ba (guard avoids OOB read past ba[Kout)) ---
#pragma unroll
    for (int t = 0; t < 8; t++)
#pragma unroll
        for (int r = 0; r < 4; r++)
            Ct[(lrow0 + r) * 132 + t * 16 + m16] = acc4[t][r];
    __syncthreads();
    for (int idx = tid; idx < 64 * 32; idx += 256) {
        int lr = idx >> 5, c4 = idx & 31;
        long grow = row0blk + lr;
        if (grow >= M) continue;
        int col = c4 * 4;
        float4 v = *(const float4*)&Ct[lr * 132 + col];
        if (col + 4 <= Kout) {
            float4 bb = *(const float4*)&ba[col];
            v.x += bb.x; v.y += bb.y; v.z += bb.z; v.w += bb.w;
        }
        __half2 p01 = __floats2half2_rn(v.x, v.y);
        __half2 p23 = __floats2half2_rn(v.z, v.w);
        uint2 u;
        u.x = *(unsigned int*)&p01;
        u.y = *(unsigned int*)&p23;
        *(uint2*)&ChR[grow * DP + col] = u;
    }
}

// ---------------- BN stats over h2 (DP stride) ----------------
__global__ __launch_bounds__(512) void bnstats_kernel(const __half* __restrict__ h,
                                                      float* __restrict__ bnsum,
                                                      float* __restrict__ bnsq, int n) {
    __shared__ float2 sred[512], qred[512];
    int tid = threadIdx.x;
    int col2 = tid & 63;
    int rgrp = tid >> 6;                      // 8 row groups
    float2 s = make_float2(0.f, 0.f), qv = make_float2(0.f, 0.f);
    if (col2 < 52) {
        for (int r = blockIdx.x * 8 + rgrp; r < n; r += gridDim.x * 8) {
            __half2 hv = *(const __half2*)&h[(long)r * DP + col2 * 2];
            float2 f = __half22float2(hv);
            s.x += f.x; s.y += f.y;
            qv.x += f.x * f.x; qv.y += f.y * f.y;
        }
    }
    sred[tid] = s; qred[tid] = qv;
    __syncthreads();
    if (tid < 52) {
        float2 ts = make_float2(0.f, 0.f), tq = make_float2(0.f, 0.f);
#pragma unroll
        for (int gg = 0; gg < 8; gg++) {
            float2 v = sred[gg * 64 + tid]; ts.x += v.x; ts.y += v.y;
            v = qred[gg * 64 + tid]; tq.x += v.x; tq.y += v.y;
        }
        atomicAdd(&bnsum[tid * 2], ts.x);
        atomicAdd(&bnsum[tid * 2 + 1], ts.y);
        atomicAdd(&bnsq[tid * 2], tq.x);
        atomicAdd(&bnsq[tid * 2 + 1], tq.y);
    }
}

// ---------------- bn prep ----------------
__global__ void bn_prep_kernel(const float* __restrict__ sum, const float* __restrict__ sq,
                               const float* __restrict__ gamma, const float* __restrict__ beta,
                               float* __restrict__ scale, float* __restrict__ shift, int n) {
    int c = threadIdx.x;
    float sc = 0.f, sh = 0.f;
    if (c < DIM) {
        float inv_n = 1.0f / (float)n;
        float mu = sum[c] * inv_n;
        float var = sq[c] * inv_n - mu * mu;
        float rs = rsqrtf(var + EPSBN);
        sc = rs * gamma[c];
        sh = beta[c] - mu * sc;
    }
    scale[c] = sc;
    shift[c] = sh;
}

// ---------------- graph boundaries ----------------
__global__ void gbounds_kernel(const int* __restrict__ batch, int* __restrict__ gstart, int n) {
    int g = threadIdx.x;
    int lo = 0, hi = n;
    while (lo < hi) {
        int mid = (lo + hi) >> 1;
        if (batch[mid] < g) lo = mid + 1; else hi = mid;
    }
    gstart[g] = lo;
    if (g == 0) gstart[NGRAPH] = n;
}

// ---------------- global add pool (fp16 input, DP stride) ----------------
__global__ __launch_bounds__(512) void pool_kernel(const __half* __restrict__ a,
                                                   const int* __restrict__ gstart,
                                                   float* __restrict__ g) {
    __shared__ float2 red[512];
    int b = blockIdx.x, tid = threadIdx.x;
    int col2 = tid & 63;
    int rgrp = tid >> 6;
    int lo = gstart[b], hi = gstart[b + 1];
    float2 s = make_float2(0.f, 0.f);
    for (int r = lo + rgrp; r < hi; r += 8) {
        __half2 h = *(const __half2*)&a[(long)r * DP + col2 * 2];
        float2 f = __half22float2(h);
        s.x += f.x; s.y += f.y;
    }
    red[tid] = s;
    __syncthreads();
    if (tid < 64) {
        float2 t = make_float2(0.f, 0.f);
#pragma unroll
        for (int gg = 0; gg < 8; gg++) {
            float2 v = red[gg * 64 + tid];
            t.x += v.x; t.y += v.y;
        }
        *(float2*)&g[b * DP + tid * 2] = t;
    }
}

// ---------------- fused MLP head ----------------
__global__ __launch_bounds__(256) void mlp_kernel(
        const float* __restrict__ g,
        const float* __restrict__ Wf1, const float* __restrict__ bf1,
        const float* __restrict__ Wf2, const float* __restrict__ bf2,
        const float* __restrict__ Wf3, const float* __restrict__ bf3,
        const float* __restrict__ Wf4, const float* __restrict__ bf4,
        float* __restrict__ out) {
    __shared__ float a0[100], a1[200], a2[300], a3[200], red[256];
    int b = blockIdx.x, tid = threadIdx.x;
    if (tid < 100) a0[tid] = g[b * DP + tid];
    __syncthreads();
    for (int c = tid; c < 200; c += 256) {
        float s = bf1[c];
        for (int k = 0; k < 100; k++) s += a0[k] * Wf1[k * 200 + c];
        a1[c] = fmaxf(s, 0.f);
    }
    __syncthreads();
    for (int c = tid; c < 300; c += 256) {
        float s = bf2[c];
        for (int k = 0; k < 200; k++) s += a1[k] * Wf2[k * 300 + c];
        a2[c] = fmaxf(s, 0.f);
    }
    __syncthreads();
    for (int c = tid; c < 200; c += 256) {
        float s = bf3[c];
        for (int k = 0; k < 300; k++) s += a2[k] * Wf3[k * 200 + c];
        a3[c] = fmaxf(s, 0.f);
    }
    __syncthreads();
    red[tid] = (tid < 200) ? a3[tid] * Wf4[tid] : 0.f;
    __syncthreads();
    for (int o = 128; o > 0; o >>= 1) {
        if (tid < o) red[tid] += red[tid + o];
        __syncthreads();
    }
    if (tid == 0) out[b] = red[0] + bf4[0];
}

extern "C" void kernel_launch(void* const* d_in, const int* in_sizes, int n_in,
                              void* d_out, int out_size, void* d_ws, size_t ws_size,
                              hipStream_t stream) {
    const float* x      = (const float*)d_in[0];
    const int*   src    = (const int*)d_in[1];
    const int*   dst    = (const int*)d_in[2];
    const int*   batch  = (const int*)d_in[3];
    const float* W1     = (const float*)d_in[4];
    const float* b1     = (const float*)d_in[5];
    const float* W2     = (const float*)d_in[6];
    const float* b2     = (const float*)d_in[7];
    const float* gamma  = (const float*)d_in[8];
    const float* beta   = (const float*)d_in[9];
    const float* Wa_init= (const float*)d_in[10];
    const float* Wa_root= (const float*)d_in[11];
    const float* ba     = (const float*)d_in[12];
    const float* Wf1    = (const float*)d_in[13];
    const float* bf1    = (const float*)d_in[14];
    const float* Wf2    = (const float*)d_in[15];
    const float* bf2    = (const float*)d_in[16];
    const float* Wf3    = (const float*)d_in[17];
    const float* bf3    = (const float*)d_in[18];
    const float* Wf4    = (const float*)d_in[19];
    const float* bf4    = (const float*)d_in[20];
    float* out = (float*)d_out;

    const int n = NNODES;
    const int e = NEDGES;

    char* ws = (char*)d_ws;
    auto carve = [&](size_t bytes) -> void* {
        void* p = (void*)ws;
        ws += (bytes + 255) & ~(size_t)255;
        return p;
    };
    __half* buf0    = (__half*)carve((size_t)n * DP * 2);   // Y1 / Y2 / P1
    __half* buf1    = (__half*)carve((size_t)n * DP * 2);   // H1 / H2
    __half* bufR    = (__half*)carve((size_t)n * DP * 2);   // R
    __half* bufC    = (__half*)carve((size_t)n * DP * 2);   // ARMA out
    _Float16* Wt1   = (_Float16*)carve((size_t)DP * DP * 2);
    _Float16* Wt2   = (_Float16*)carve((size_t)DP * DP * 2);
    _Float16* Wt3   = (_Float16*)carve((size_t)DP * DP * 2);
    _Float16* Wt4   = (_Float16*)carve((size_t)DP * DP * 2);
    int*    off     = (int*)carve((size_t)(n + 1) * 4);
    int*    btotal  = (int*)carve((size_t)NBUK * 4);
    int*    bbase   = (int*)carve((size_t)(NBUK + 1) * 4);
    int*    bcursor = (int*)carve((size_t)NBUK * 4);
    int*    ssorted = (int*)carve((size_t)e * 4);
    int2*   gpairs  = (int2*)carve((size_t)e * 8);
    float*  dinv_sl = (float*)carve((size_t)n * 4);
    float*  dinv_nsl= (float*)carve((size_t)n * 4);
    float*  bnsum   = (float*)carve(DP * 4);
    float*  bnsq    = (float*)carve(DP * 4);
    float*  bnscale = (float*)carve(DP * 4);
    float*  bnshift = (float*)carve(DP * 4);
    float*  b1p     = (float*)carve(DP * 4);
    float*  b2p     = (float*)carve(DP * 4);
    int*    gstart  = (int*)carve((size_t)(NGRAPH + 1) * 4);
    float*  gpool   = (float*)carve((size_t)NGRAPH * DP * 4);

    const int nchunk = (e + BINCH - 1) / BINCH;

    // ---- pack weights + pad biases ----
    packW4_kernel<<<256, 256, 0, stream>>>(W1, W2, Wa_init, Wa_root, Wt1, Wt2, Wt3, Wt4);
    padb_kernel<<<1, 128, 0, stream>>>(b1, b2, b1p, b2p);

    // ---- build CSR by dst ----
    hipMemsetAsync(btotal, 0, (size_t)NBUK * 4, stream);
    hipMemsetAsync(bnsum, 0, DP * 4, stream);
    hipMemsetAsync(bnsq, 0, DP * 4, stream);
    bin_count_kernel<<<nchunk, 256, 0, stream>>>(dst, btotal, e);
    bucket_scan_kernel<<<1, 512, 0, stream>>>(btotal, bbase, bcursor, e);
    bin_kernel<<<nchunk, 256, 0, stream>>>(src, dst, bcursor, gpairs, e);
    bucket_build_kernel<<<NBUK, 256, 0, stream>>>(gpairs, bbase, off, ssorted, dinv_sl, dinv_nsl, n, e);
    gbounds_kernel<<<1, 512, 0, stream>>>(batch, gstart, n);

    const int prop_blocks = (n + 3) / 4;
    const int mm_blocks = (n + 63) / 64;

    // ---- SGConv 1 (matmul first: prop(x)@W1 == prop(x@W1)) ----
    matmul_a32_kernel<<<mm_blocks, 256, 0, stream>>>(x, Wt1, dinv_sl, buf0, n);          // Y1 = (x@W1)*dsl
    prop_kernel<<<prop_blocks, 256, 0, stream>>>(buf0, ssorted, off, dinv_sl, b1p, buf1, n);  // H1 = relu(prop+b1)

    // ---- SGConv 2 ----
    matmul_a16_kernel<<<mm_blocks, 256, 0, stream>>>(buf1, Wt2, dinv_sl, buf0, n);       // Y2 = (H1@W2)*dsl
    prop_kernel<<<prop_blocks, 256, 0, stream>>>(buf0, ssorted, off, dinv_sl, b2p, buf1, n);  // H2 = relu(prop+b2)

    // ---- BatchNorm stats + params ----
    bnstats_kernel<<<512, 512, 0, stream>>>(buf1, bnsum, bnsq, n);
    bn_prep_kernel<<<1, 128, 0, stream>>>(bnsum, bnsq, gamma, beta, bnscale, bnshift, n);

    // ---- ARMAConv: dual matmul with fused BN, then prop with fused add+relu ----
    matmul_dual_kernel<<<mm_blocks, 256, 0, stream>>>(buf1, Wt3, Wt4, ba, dinv_nsl, bnscale, bnshift, buf0, bufR, n, DIM);
    prop_arma_kernel<<<prop_blocks, 256, 0, stream>>>(buf0, ssorted, off, dinv_nsl, bufR, bufC, n);

    // ---- global add pool ----
    pool_kernel<<<NGRAPH, 512, 0, stream>>>(bufC, gstart, gpool);

    // ---- MLP head ----
    mlp_kernel<<<NGRAPH, 256, 0, stream>>>(gpool, Wf1, bf1, Wf2, bf2, Wf3, bf3, Wf4, bf4, out);
}

// Round 5
// 503.295 us; speedup vs baseline: 7.5318x; 1.0573x over previous
//
#include <hip/hip_runtime.h>
#include <hip/hip_fp16.h>

#define NNODES 100000
#define NEDGES 1600000
#define NGRAPH 512
#define DIM    100
#define DP     128
#define EPSBN  1e-5f
#define NBUK   ((NNODES + 255) >> 8)
#define BINCH  8192

typedef _Float16 half8 __attribute__((ext_vector_type(8)));
typedef float floatx4 __attribute__((ext_vector_type(4)));

// ---------------- pass 0: per-chunk bucket counts ----------------
__global__ __launch_bounds__(256) void bin_count_kernel(const int* __restrict__ dst,
                                                        int* __restrict__ btotal, int e) {
    __shared__ int lc[NBUK];
    int tid = threadIdx.x;
    int base = blockIdx.x * BINCH;
    int m = e - base; if (m > BINCH) m = BINCH;
    for (int b = tid; b < NBUK; b += 256) lc[b] = 0;
    __syncthreads();
    for (int j = tid; j < m; j += 256)
        atomicAdd(&lc[dst[base + j] >> 8], 1);
    __syncthreads();
    for (int b = tid; b < NBUK; b += 256)
        if (lc[b]) atomicAdd(&btotal[b], lc[b]);
}

// ---------------- bucket exclusive scan + graph boundaries (fused) ----------------
__global__ void bucket_scan_kernel(const int* __restrict__ btotal, int* __restrict__ bbase,
                                   int* __restrict__ bcursor, int e,
                                   const int* __restrict__ batch, int* __restrict__ gstart, int n) {
    __shared__ int s[512];
    int tid = threadIdx.x;
    int v = (tid < NBUK) ? btotal[tid] : 0;
    s[tid] = v; __syncthreads();
    for (int o = 1; o < 512; o <<= 1) {
        int t = (tid >= o) ? s[tid - o] : 0;
        __syncthreads();
        s[tid] += t;
        __syncthreads();
    }
    if (tid < NBUK) {
        int base = s[tid] - v;
        bbase[tid] = base;
        bcursor[tid] = base;
    }
    if (tid == 0) bbase[NBUK] = e;

    // graph boundaries (independent work, same tiny kernel)
    {
        int g = tid;
        int lo = 0, hi = n;
        while (lo < hi) {
            int mid = (lo + hi) >> 1;
            if (batch[mid] < g) lo = mid + 1; else hi = mid;
        }
        gstart[g] = lo;
        if (g == 0) gstart[NGRAPH] = n;
    }
}

// ---------------- pass 1: bin pairs bucket-major (packed output) ----------------
__global__ __launch_bounds__(256) void bin_kernel(
        const int* __restrict__ src, const int* __restrict__ dst,
        int* __restrict__ bcursor, unsigned int* __restrict__ gpairs, int e) {
    __shared__ int2 lpairs[BINCH];
    __shared__ int lcount[NBUK], lstart[NBUK], lcur[NBUK], gbase[NBUK];
    int tid = threadIdx.x;
    int base = blockIdx.x * BINCH;
    int m = e - base; if (m > BINCH) m = BINCH;

    for (int b = tid; b < NBUK; b += 256) lcount[b] = 0;
    __syncthreads();
    for (int j = tid; j < m; j += 256)
        atomicAdd(&lcount[dst[base + j] >> 8], 1);
    __syncthreads();
    if (tid == 0) {
        int acc = 0;
        for (int b = 0; b < NBUK; b++) {
            lstart[b] = acc;
            lcur[b] = acc;
            acc += lcount[b];
        }
    }
    __syncthreads();
    for (int b = tid; b < NBUK; b += 256)
        gbase[b] = atomicAdd(&bcursor[b], lcount[b]);
    for (int j = tid; j < m; j += 256) {
        int s = src[base + j], d = dst[base + j];
        int p = atomicAdd(&lcur[d >> 8], 1);
        lpairs[p] = make_int2(s, d);
    }
    __syncthreads();
    for (int j = tid; j < m; j += 256) {
        int2 pr = lpairs[j];
        int b = pr.y >> 8;
        gpairs[gbase[b] + (j - lstart[b])] =
            ((unsigned int)pr.x << 8) | ((unsigned int)pr.y & 255u);
    }
}

// ---------------- pass 2: fused per-bucket build (packed input) ----------------
__global__ __launch_bounds__(256) void bucket_build_kernel(
        const unsigned int* __restrict__ gpairs, const int* __restrict__ bbase,
        int* __restrict__ off, int* __restrict__ ssorted,
        float* __restrict__ dsl, float* __restrict__ dnsl, int n, int e) {
    __shared__ int cnt[256];
    __shared__ int sc[256];
    int b = blockIdx.x, tid = threadIdx.x;
    int node0 = b << 8;
    int e0 = bbase[b], e1 = bbase[b + 1];

    cnt[tid] = 0;
    __syncthreads();
    for (int j = e0 + tid; j < e1; j += 256)
        atomicAdd(&cnt[gpairs[j] & 255u], 1);
    __syncthreads();

    int c = cnt[tid];
    sc[tid] = c; __syncthreads();
    for (int o = 1; o < 256; o <<= 1) {
        int t = (tid >= o) ? sc[tid - o] : 0;
        __syncthreads();
        sc[tid] += t;
        __syncthreads();
    }
    int excl = sc[tid] - c;

    int node = node0 + tid;
    if (node < n) {
        off[node] = e0 + excl;
        float cf = (float)c;
        dsl[node] = rsqrtf(cf + 1.0f);
        dnsl[node] = (c > 0) ? rsqrtf(cf) : 0.0f;
    }
    if (b == NBUK - 1 && tid == 0) off[n] = e;

    __syncthreads();
    cnt[tid] = e0 + excl;
    __syncthreads();
    for (int j = e0 + tid; j < e1; j += 256) {
        unsigned int pk = gpairs[j];
        int p = atomicAdd(&cnt[pk & 255u], 1);
        ssorted[p] = (int)(pk >> 8);
    }
}

// ---------------- pack all 4 W into MFMA fragment order + aux init block ----------------
__global__ void packW4_kernel(const float* __restrict__ W1, const float* __restrict__ W2,
                              const float* __restrict__ W3, const float* __restrict__ W4,
                              _Float16* __restrict__ Wt1, _Float16* __restrict__ Wt2,
                              _Float16* __restrict__ Wt3, _Float16* __restrict__ Wt4,
                              const float* __restrict__ b1, const float* __restrict__ b2,
                              float* __restrict__ b1p, float* __restrict__ b2p,
                              int* __restrict__ btotal, float* __restrict__ bnsum,
                              float* __restrict__ bnsq, __half* __restrict__ buf0zr) {
    if (blockIdx.x == 256) {
        // aux: pad biases, zero counters, zero gather pad-row
        int t = threadIdx.x;
        if (t < 128) {
            b1p[t] = (t < DIM) ? b1[t] : 0.f;
            b2p[t] = (t < DIM) ? b2[t] : 0.f;
            bnsum[t] = 0.f;
            bnsq[t] = 0.f;
        }
        for (int i = t; i < NBUK; i += 256) btotal[i] = 0;
        if (t < 64) ((unsigned int*)buf0zr)[t] = 0u;   // row n of buf0 = zeros (256 B)
        return;
    }
    int which = blockIdx.x >> 6;          // 64 blocks per weight
    int idx = (blockIdx.x & 63) * 256 + threadIdx.x;
    const float* W = (which == 0) ? W1 : (which == 1) ? W2 : (which == 2) ? W3 : W4;
    _Float16* Wt  = (which == 0) ? Wt1 : (which == 1) ? Wt2 : (which == 2) ? Wt3 : Wt4;
    int K = (which == 0) ? 128 : DIM;
    int j = idx & 7;
    int l = (idx >> 3) & 63;
    int c = idx >> 9;
    int t = c >> 2, k0 = c & 3;
    int nn = t * 16 + (l & 15);
    int k = k0 * 32 + (l >> 4) * 8 + j;
    float v = (k < K && nn < DIM) ? W[k * DIM + nn] : 0.f;
    Wt[idx] = (_Float16)v;
}

// ---------------- propagation (self-loop) : out = relu(dinv*sum + bias) ----------------
// All gather steps run the 16-wide ILP-4 path; invalid slots read the zero row (ZR=n).
__global__ __launch_bounds__(256) void prop_kernel(
        const __half* __restrict__ pre, const int* __restrict__ ssorted,
        const int* __restrict__ off, const float* __restrict__ dinv,
        const float* __restrict__ bias, __half* __restrict__ outH, int n) {
    int wave = (blockIdx.x * blockDim.x + threadIdx.x) >> 6;
    int lane = threadIdx.x & 63;
    if (wave >= n) return;
    int e0 = off[wave], e1 = off[wave + 1];
    int deg = e1 - e0;
    int g = lane >> 4;
    int q = lane & 15;
    const int ZR = n;

    float acc[8];
#pragma unroll
    for (int i = 0; i < 8; i++) acc[i] = 0.f;

    auto addu = [&](uint4 u) {
        float2 f;
        f = __half22float2(*(__half2*)&u.x); acc[0] += f.x; acc[1] += f.y;
        f = __half22float2(*(__half2*)&u.y); acc[2] += f.x; acc[3] += f.y;
        f = __half22float2(*(__half2*)&u.z); acc[4] += f.x; acc[5] += f.y;
        f = __half22float2(*(__half2*)&u.w); acc[6] += f.x; acc[7] += f.y;
    };
    auto rowptr = [&](int s) -> const uint4* {
        return (const uint4*)&pre[(long)s * DP + q * 8];
    };

    for (int base = 0; base < deg; base += 64) {
        int m = deg - base; if (m > 64) m = 64;
        int sidx = (lane < m) ? ssorted[e0 + base + lane] : ZR;
        for (int j = 0; j < m; j += 16) {
            int s0 = __shfl(sidx, j + g);
            int s1 = __shfl(sidx, j + 4 + g);
            int s2 = __shfl(sidx, j + 8 + g);
            int s3 = __shfl(sidx, j + 12 + g);
            uint4 u0 = *rowptr(s0);
            uint4 u1 = *rowptr(s1);
            uint4 u2 = *rowptr(s2);
            uint4 u3 = *rowptr(s3);
            addu(u0); addu(u1); addu(u2); addu(u3);
        }
    }

#pragma unroll
    for (int i = 0; i < 8; i++) {
        acc[i] += __shfl_xor(acc[i], 16);
        acc[i] += __shfl_xor(acc[i], 32);
    }

    if (g == 0) {
        float dn = dinv[wave];
        addu(*rowptr(wave));                // self-loop (pre already dsl-scaled)
        float4 b0 = *(const float4*)&bias[q * 8];
        float4 b1v = *(const float4*)&bias[q * 8 + 4];
        float o[8];
        o[0] = fmaxf(dn * acc[0] + b0.x, 0.f);
        o[1] = fmaxf(dn * acc[1] + b0.y, 0.f);
        o[2] = fmaxf(dn * acc[2] + b0.z, 0.f);
        o[3] = fmaxf(dn * acc[3] + b0.w, 0.f);
        o[4] = fmaxf(dn * acc[4] + b1v.x, 0.f);
        o[5] = fmaxf(dn * acc[5] + b1v.y, 0.f);
        o[6] = fmaxf(dn * acc[6] + b1v.z, 0.f);
        o[7] = fmaxf(dn * acc[7] + b1v.w, 0.f);
        __half2 p0 = __floats2half2_rn(o[0], o[1]);
        __half2 p1 = __floats2half2_rn(o[2], o[3]);
        __half2 p2 = __floats2half2_rn(o[4], o[5]);
        __half2 p3 = __floats2half2_rn(o[6], o[7]);
        uint4 u;
        u.x = *(unsigned int*)&p0;
        u.y = *(unsigned int*)&p1;
        u.z = *(unsigned int*)&p2;
        u.w = *(unsigned int*)&p3;
        *(uint4*)&outH[(long)wave * DP + q * 8] = u;
    }
}

// ---------------- ARMA prop: out = relu(dinv*sum + R), no self-loop ----------------
__global__ __launch_bounds__(256) void prop_arma_kernel(
        const __half* __restrict__ pre, const int* __restrict__ ssorted,
        const int* __restrict__ off, const float* __restrict__ dinv,
        const __half* __restrict__ R, __half* __restrict__ outH, int n) {
    int wave = (blockIdx.x * blockDim.x + threadIdx.x) >> 6;
    int lane = threadIdx.x & 63;
    if (wave >= n) return;
    int e0 = off[wave], e1 = off[wave + 1];
    int deg = e1 - e0;
    int g = lane >> 4;
    int q = lane & 15;
    const int ZR = n;

    float acc[8];
#pragma unroll
    for (int i = 0; i < 8; i++) acc[i] = 0.f;

    auto addu = [&](uint4 u) {
        float2 f;
        f = __half22float2(*(__half2*)&u.x); acc[0] += f.x; acc[1] += f.y;
        f = __half22float2(*(__half2*)&u.y); acc[2] += f.x; acc[3] += f.y;
        f = __half22float2(*(__half2*)&u.z); acc[4] += f.x; acc[5] += f.y;
        f = __half22float2(*(__half2*)&u.w); acc[6] += f.x; acc[7] += f.y;
    };
    auto rowptr = [&](int s) -> const uint4* {
        return (const uint4*)&pre[(long)s * DP + q * 8];
    };

    for (int base = 0; base < deg; base += 64) {
        int m = deg - base; if (m > 64) m = 64;
        int sidx = (lane < m) ? ssorted[e0 + base + lane] : ZR;
        for (int j = 0; j < m; j += 16) {
            int s0 = __shfl(sidx, j + g);
            int s1 = __shfl(sidx, j + 4 + g);
            int s2 = __shfl(sidx, j + 8 + g);
            int s3 = __shfl(sidx, j + 12 + g);
            uint4 u0 = *rowptr(s0);
            uint4 u1 = *rowptr(s1);
            uint4 u2 = *rowptr(s2);
            uint4 u3 = *rowptr(s3);
            addu(u0); addu(u1); addu(u2); addu(u3);
        }
    }

#pragma unroll
    for (int i = 0; i < 8; i++) {
        acc[i] += __shfl_xor(acc[i], 16);
        acc[i] += __shfl_xor(acc[i], 32);
    }

    if (g == 0) {
        float dn = dinv[wave];
        uint4 r4 = *(const uint4*)&R[(long)wave * DP + q * 8];
        float rr[8];
        float2 f;
        f = __half22float2(*(__half2*)&r4.x); rr[0] = f.x; rr[1] = f.y;
        f = __half22float2(*(__half2*)&r4.y); rr[2] = f.x; rr[3] = f.y;
        f = __half22float2(*(__half2*)&r4.z); rr[4] = f.x; rr[5] = f.y;
        f = __half22float2(*(__half2*)&r4.w); rr[6] = f.x; rr[7] = f.y;
        float o[8];
#pragma unroll
        for (int i = 0; i < 8; i++) o[i] = fmaxf(dn * acc[i] + rr[i], 0.f);
        __half2 p0 = __floats2half2_rn(o[0], o[1]);
        __half2 p1 = __floats2half2_rn(o[2], o[3]);
        __half2 p2 = __floats2half2_rn(o[4], o[5]);
        __half2 p3 = __floats2half2_rn(o[6], o[7]);
        uint4 u;
        u.x = *(unsigned int*)&p0;
        u.y = *(unsigned int*)&p1;
        u.z = *(unsigned int*)&p2;
        u.w = *(unsigned int*)&p3;
        *(uint4*)&outH[(long)wave * DP + q * 8] = u;
    }
}

// ---------------- MFMA matmul, fp32 A (x input): C = (A@W) * rowscale -> fp16 DP ----------------
__global__ __launch_bounds__(256) void matmul_a32_kernel(
        const float* __restrict__ A, const _Float16* __restrict__ WtF,
        const float* __restrict__ rowscale, __half* __restrict__ Ch, int M) {
    __shared__ char smraw[64 * 132 * 4];
    _Float16* Bs = (_Float16*)smraw;
    float* Ct = (float*)smraw;
    int tid = threadIdx.x;
    int wave = tid >> 6;
    int lane = tid & 63;
    int m16 = lane & 15;
    int quad = lane >> 4;
    long row0blk = (long)blockIdx.x * 64;
    long row0 = row0blk + wave * 16;

    {
        const uint4* s = (const uint4*)WtF;
        uint4* d = (uint4*)Bs;
        for (int i = tid; i < 2048; i += 256) d[i] = s[i];
    }

    half8 af[4];
    {
        long ar = row0 + m16; if (ar >= M) ar = M - 1;
        const float* Ap = &A[ar * DP + quad * 8];
#pragma unroll
        for (int k0 = 0; k0 < 4; k0++) {
            float4 v0 = *(const float4*)(Ap + k0 * 32);
            float4 v1 = *(const float4*)(Ap + k0 * 32 + 4);
            half8 o;
            o[0] = (_Float16)v0.x; o[1] = (_Float16)v0.y;
            o[2] = (_Float16)v0.z; o[3] = (_Float16)v0.w;
            o[4] = (_Float16)v1.x; o[5] = (_Float16)v1.y;
            o[6] = (_Float16)v1.z; o[7] = (_Float16)v1.w;
            af[k0] = o;
        }
    }
    __syncthreads();

    floatx4 acc[8];
#pragma unroll
    for (int t = 0; t < 8; t++) acc[t] = (floatx4){0.f, 0.f, 0.f, 0.f};

#pragma unroll
    for (int c = 0; c < 32; c++) {
        half8 bf = *(const half8*)&Bs[(c * 64 + lane) * 8];
        acc[c >> 2] = __builtin_amdgcn_mfma_f32_16x16x32_f16(af[c & 3], bf, acc[c >> 2], 0, 0, 0);
    }
    __syncthreads();

    int lrow0 = wave * 16 + quad * 4;
#pragma unroll
    for (int t = 0; t < 8; t++)
#pragma unroll
        for (int r = 0; r < 4; r++)
            Ct[(lrow0 + r) * 132 + t * 16 + m16] = acc[t][r];
    __syncthreads();

    for (int idx = tid; idx < 64 * 32; idx += 256) {
        int lr = idx >> 5, c4 = idx & 31;
        long grow = row0blk + lr;
        if (grow >= M) continue;
        int col = c4 * 4;
        float4 v = *(const float4*)&Ct[lr * 132 + col];
        float rs = rowscale[grow];
        v.x *= rs; v.y *= rs; v.z *= rs; v.w *= rs;
        __half2 p01 = __floats2half2_rn(v.x, v.y);
        __half2 p23 = __floats2half2_rn(v.z, v.w);
        uint2 u;
        u.x = *(unsigned int*)&p01;
        u.y = *(unsigned int*)&p23;
        *(uint2*)&Ch[grow * DP + col] = u;
    }
}

// ---------------- MFMA matmul, fp16 A (DP stride): C = (A@W) * rowscale -> fp16 DP ----------------
__global__ __launch_bounds__(256) void matmul_a16_kernel(
        const __half* __restrict__ A, const _Float16* __restrict__ WtF,
        const float* __restrict__ rowscale, __half* __restrict__ Ch, int M) {
    __shared__ char smraw[64 * 132 * 4];
    _Float16* Bs = (_Float16*)smraw;
    float* Ct = (float*)smraw;
    int tid = threadIdx.x;
    int wave = tid >> 6;
    int lane = tid & 63;
    int m16 = lane & 15;
    int quad = lane >> 4;
    long row0blk = (long)blockIdx.x * 64;
    long row0 = row0blk + wave * 16;

    {
        const uint4* s = (const uint4*)WtF;
        uint4* d = (uint4*)Bs;
        for (int i = tid; i < 2048; i += 256) d[i] = s[i];
    }

    half8 af[4];
    {
        long ar = row0 + m16; if (ar >= M) ar = M - 1;
        const _Float16* Ap = (const _Float16*)&A[ar * DP + quad * 8];
#pragma unroll
        for (int k0 = 0; k0 < 4; k0++)
            af[k0] = *(const half8*)(Ap + k0 * 32);
    }
    __syncthreads();

    floatx4 acc[8];
#pragma unroll
    for (int t = 0; t < 8; t++) acc[t] = (floatx4){0.f, 0.f, 0.f, 0.f};

#pragma unroll
    for (int c = 0; c < 32; c++) {
        half8 bf = *(const half8*)&Bs[(c * 64 + lane) * 8];
        acc[c >> 2] = __builtin_amdgcn_mfma_f32_16x16x32_f16(af[c & 3], bf, acc[c >> 2], 0, 0, 0);
    }
    __syncthreads();

    int lrow0 = wave * 16 + quad * 4;
#pragma unroll
    for (int t = 0; t < 8; t++)
#pragma unroll
        for (int r = 0; r < 4; r++)
            Ct[(lrow0 + r) * 132 + t * 16 + m16] = acc[t][r];
    __syncthreads();

    for (int idx = tid; idx < 64 * 32; idx += 256) {
        int lr = idx >> 5, c4 = idx & 31;
        long grow = row0blk + lr;
        if (grow >= M) continue;
        int col = c4 * 4;
        float4 v = *(const float4*)&Ct[lr * 132 + col];
        float rs = rowscale[grow];
        v.x *= rs; v.y *= rs; v.z *= rs; v.w *= rs;
        __half2 p01 = __floats2half2_rn(v.x, v.y);
        __half2 p23 = __floats2half2_rn(v.z, v.w);
        uint2 u;
        u.x = *(unsigned int*)&p01;
        u.y = *(unsigned int*)&p23;
        *(uint2*)&Ch[grow * DP + col] = u;
    }
}

// ---------------- dual MFMA matmul with fused BN on A: P1 = BN(A)@W3*rowscale ; R = BN(A)@W4 + ba ----------------
__global__ __launch_bounds__(256) void matmul_dual_kernel(
        const __half* __restrict__ A, const _Float16* __restrict__ WtF3,
        const _Float16* __restrict__ WtF4, const float* __restrict__ ba,
        const float* __restrict__ rowscale,
        const float* __restrict__ bnscale, const float* __restrict__ bnshift,
        __half* __restrict__ Ch1, __half* __restrict__ ChR, int M, int Kout) {
    __shared__ char smraw[64 * 132 * 4];
    _Float16* Bs = (_Float16*)smraw;
    float* Ct = (float*)smraw;
    int tid = threadIdx.x;
    int wave = tid >> 6;
    int lane = tid & 63;
    int m16 = lane & 15;
    int quad = lane >> 4;
    long row0blk = (long)blockIdx.x * 64;
    long row0 = row0blk + wave * 16;

    half8 af[4];
    {
        long ar = row0 + m16; if (ar >= M) ar = M - 1;
        const _Float16* Ap = (const _Float16*)&A[ar * DP + quad * 8];
#pragma unroll
        for (int k0 = 0; k0 < 4; k0++) {
            half8 h = *(const half8*)(Ap + k0 * 32);
            int c0 = quad * 8 + k0 * 32;
            float4 sc0 = *(const float4*)&bnscale[c0];
            float4 sc1 = *(const float4*)&bnscale[c0 + 4];
            float4 sh0 = *(const float4*)&bnshift[c0];
            float4 sh1 = *(const float4*)&bnshift[c0 + 4];
            half8 o;
            o[0] = (_Float16)((float)h[0] * sc0.x + sh0.x);
            o[1] = (_Float16)((float)h[1] * sc0.y + sh0.y);
            o[2] = (_Float16)((float)h[2] * sc0.z + sh0.z);
            o[3] = (_Float16)((float)h[3] * sc0.w + sh0.w);
            o[4] = (_Float16)((float)h[4] * sc1.x + sh1.x);
            o[5] = (_Float16)((float)h[5] * sc1.y + sh1.y);
            o[6] = (_Float16)((float)h[6] * sc1.z + sh1.z);
            o[7] = (_Float16)((float)h[7] * sc1.w + sh1.w);
            af[k0] = o;
        }
    }

    floatx4 acc3[8], acc4[8];
#pragma unroll
    for (int t = 0; t < 8; t++) {
        acc3[t] = (floatx4){0.f, 0.f, 0.f, 0.f};
        acc4[t] = (floatx4){0.f, 0.f, 0.f, 0.f};
    }

    // --- W3 pass ---
    {
        const uint4* s = (const uint4*)WtF3;
        uint4* d = (uint4*)Bs;
        for (int i = tid; i < 2048; i += 256) d[i] = s[i];
    }
    __syncthreads();
#pragma unroll
    for (int c = 0; c < 32; c++) {
        half8 bf = *(const half8*)&Bs[(c * 64 + lane) * 8];
        acc3[c >> 2] = __builtin_amdgcn_mfma_f32_16x16x32_f16(af[c & 3], bf, acc3[c >> 2], 0, 0, 0);
    }
    __syncthreads();

    // --- W4 pass ---
    {
        const uint4* s = (const uint4*)WtF4;
        uint4* d = (uint4*)Bs;
        for (int i = tid; i < 2048; i += 256) d[i] = s[i];
    }
    __syncthreads();
#pragma unroll
    for (int c = 0; c < 32; c++) {
        half8 bf = *(const half8*)&Bs[(c * 64 + lane) * 8];
        acc4[c >> 2] = __builtin_amdgcn_mfma_f32_16x16x32_f16(af[c & 3], bf, acc4[c >> 2], 0, 0, 0);
    }
    __syncthreads();

    int lrow0 = wave * 16 + quad * 4;

    // --- P1 epilogue: rowscale only ---
#pragma unroll
    for (int t = 0; t < 8; t++)
#pragma unroll
        for (int r = 0; r < 4; r++)
            Ct[(lrow0 + r) * 132 + t * 16 + m16] = acc3[t][r];
    __syncthreads();
    for (int idx = tid; idx < 64 * 32; idx += 256) {
        int lr = idx >> 5, c4 = idx & 31;
        long grow = row0blk + lr;
        if (grow >= M) continue;
        int col = c4 * 4;
        float4 v = *(const float4*)&Ct[lr * 132 + col];
        float rs = rowscale[grow];
        v.x *= rs; v.y *= rs; v.z *= rs; v.w *= rs;
        __half2 p01 = __floats2half2_rn(v.x, v.y);
        __half2 p23 = __floats2half2_rn(v.z, v.w);
        uint2 u;
        u.x = *(unsigned int*)&p01;
        u.y = *(unsigned int*)&p23;
        *(uint2*)&Ch1[grow * DP + col] = u;
    }
    __syncthreads();

    // --- R epilogue: +ba ---
#pragma unroll
    for (int t = 0; t < 8; t++)
#pragma unroll
        for (int r = 0; r < 4; r++)
            Ct[(lrow0 + r) * 132 + t * 16 + m16] = acc4[t][r];
    __syncthreads();
    for (int idx = tid; idx < 64 * 32; idx += 256) {
        int lr = idx >> 5, c4 = idx & 31;
        long grow = row0blk + lr;
        if (grow >= M) continue;
        int col = c4 * 4;
        float4 v = *(const float4*)&Ct[lr * 132 + col];
        if (col + 4 <= Kout) {
            float4 bb = *(const float4*)&ba[col];
            v.x += bb.x; v.y += bb.y; v.z += bb.z; v.w += bb.w;
        }
        __half2 p01 = __floats2half2_rn(v.x, v.y);
        __half2 p23 = __floats2half2_rn(v.z, v.w);
        uint2 u;
        u.x = *(unsigned int*)&p01;
        u.y = *(unsigned int*)&p23;
        *(uint2*)&ChR[grow * DP + col] = u;
    }
}

// ---------------- BN stats over h2 (DP stride) ----------------
__global__ __launch_bounds__(512) void bnstats_kernel(const __half* __restrict__ h,
                                                      float* __restrict__ bnsum,
                                                      float* __restrict__ bnsq, int n) {
    __shared__ float2 sred[512], qred[512];
    int tid = threadIdx.x;
    int col2 = tid & 63;
    int rgrp = tid >> 6;                      // 8 row groups
    float2 s = make_float2(0.f, 0.f), qv = make_float2(0.f, 0.f);
    if (col2 < 52) {
        for (int r = blockIdx.x * 8 + rgrp; r < n; r += gridDim.x * 8) {
            __half2 hv = *(const __half2*)&h[(long)r * DP + col2 * 2];
            float2 f = __half22float2(hv);
            s.x += f.x; s.y += f.y;
            qv.x += f.x * f.x; qv.y += f.y * f.y;
        }
    }
    sred[tid] = s; qred[tid] = qv;
    __syncthreads();
    if (tid < 52) {
        float2 ts = make_float2(0.f, 0.f), tq = make_float2(0.f, 0.f);
#pragma unroll
        for (int gg = 0; gg < 8; gg++) {
            float2 v = sred[gg * 64 + tid]; ts.x += v.x; ts.y += v.y;
            v = qred[gg * 64 + tid]; tq.x += v.x; tq.y += v.y;
        }
        atomicAdd(&bnsum[tid * 2], ts.x);
        atomicAdd(&bnsum[tid * 2 + 1], ts.y);
        atomicAdd(&bnsq[tid * 2], tq.x);
        atomicAdd(&bnsq[tid * 2 + 1], tq.y);
    }
}

// ---------------- bn prep ----------------
__global__ void bn_prep_kernel(const float* __restrict__ sum, const float* __restrict__ sq,
                               const float* __restrict__ gamma, const float* __restrict__ beta,
                               float* __restrict__ scale, float* __restrict__ shift, int n) {
    int c = threadIdx.x;
    float sc = 0.f, sh = 0.f;
    if (c < DIM) {
        float inv_n = 1.0f / (float)n;
        float mu = sum[c] * inv_n;
        float var = sq[c] * inv_n - mu * mu;
        float rs = rsqrtf(var + EPSBN);
        sc = rs * gamma[c];
        sh = beta[c] - mu * sc;
    }
    scale[c] = sc;
    shift[c] = sh;
}

// ---------------- fused global add pool + MLP head ----------------
__global__ __launch_bounds__(512) void pmlp_kernel(
        const __half* __restrict__ a, const int* __restrict__ gstart,
        const float* __restrict__ Wf1, const float* __restrict__ bf1,
        const float* __restrict__ Wf2, const float* __restrict__ bf2,
        const float* __restrict__ Wf3, const float* __restrict__ bf3,
        const float* __restrict__ Wf4, const float* __restrict__ bf4,
        float* __restrict__ out) {
    __shared__ float2 red[512];
    __shared__ float gsum[128], a1[200], a2[300], a3[200], red1[512];
    int b = blockIdx.x, tid = threadIdx.x;

    // ---- pool phase ----
    {
        int col2 = tid & 63;
        int rgrp = tid >> 6;
        int lo = gstart[b], hi = gstart[b + 1];
        float2 s = make_float2(0.f, 0.f);
        for (int r = lo + rgrp; r < hi; r += 8) {
            __half2 h = *(const __half2*)&a[(long)r * DP + col2 * 2];
            float2 f = __half22float2(h);
            s.x += f.x; s.y += f.y;
        }
        red[tid] = s;
        __syncthreads();
        if (tid < 64) {
            float2 t = make_float2(0.f, 0.f);
#pragma unroll
            for (int gg = 0; gg < 8; gg++) {
                float2 v = red[gg * 64 + tid];
                t.x += v.x; t.y += v.y;
            }
            gsum[tid * 2] = t.x;
            gsum[tid * 2 + 1] = t.y;
        }
        __syncthreads();
    }

    // ---- MLP phase ----
    for (int c = tid; c < 200; c += 512) {
        float s = bf1[c];
        for (int k = 0; k < 100; k++) s += gsum[k] * Wf1[k * 200 + c];
        a1[c] = fmaxf(s, 0.f);
    }
    __syncthreads();
    for (int c = tid; c < 300; c += 512) {
        float s = bf2[c];
        for (int k = 0; k < 200; k++) s += a1[k] * Wf2[k * 300 + c];
        a2[c] = fmaxf(s, 0.f);
    }
    __syncthreads();
    for (int c = tid; c < 200; c += 512) {
        float s = bf3[c];
        for (int k = 0; k < 300; k++) s += a2[k] * Wf3[k * 200 + c];
        a3[c] = fmaxf(s, 0.f);
    }
    __syncthreads();
    red1[tid] = (tid < 200) ? a3[tid] * Wf4[tid] : 0.f;
    __syncthreads();
    for (int o = 256; o > 0; o >>= 1) {
        if (tid < o) red1[tid] += red1[tid + o];
        __syncthreads();
    }
    if (tid == 0) out[b] = red1[0] + bf4[0];
}

extern "C" void kernel_launch(void* const* d_in, const int* in_sizes, int n_in,
                              void* d_out, int out_size, void* d_ws, size_t ws_size,
                              hipStream_t stream) {
    const float* x      = (const float*)d_in[0];
    const int*   src    = (const int*)d_in[1];
    const int*   dst    = (const int*)d_in[2];
    const int*   batch  = (const int*)d_in[3];
    const float* W1     = (const float*)d_in[4];
    const float* b1     = (const float*)d_in[5];
    const float* W2     = (const float*)d_in[6];
    const float* b2     = (const float*)d_in[7];
    const float* gamma  = (const float*)d_in[8];
    const float* beta   = (const float*)d_in[9];
    const float* Wa_init= (const float*)d_in[10];
    const float* Wa_root= (const float*)d_in[11];
    const float* ba     = (const float*)d_in[12];
    const float* Wf1    = (const float*)d_in[13];
    const float* bf1    = (const float*)d_in[14];
    const float* Wf2    = (const float*)d_in[15];
    const float* bf2    = (const float*)d_in[16];
    const float* Wf3    = (const float*)d_in[17];
    const float* bf3    = (const float*)d_in[18];
    const float* Wf4    = (const float*)d_in[19];
    const float* bf4    = (const float*)d_in[20];
    float* out = (float*)d_out;

    const int n = NNODES;
    const int e = NEDGES;

    char* ws = (char*)d_ws;
    auto carve = [&](size_t bytes) -> void* {
        void* p = (void*)ws;
        ws += (bytes + 255) & ~(size_t)255;
        return p;
    };
    __half* buf0    = (__half*)carve((size_t)(n + 1) * DP * 2);  // Y1/Y2/P1 (+zero pad row n)
    __half* buf1    = (__half*)carve((size_t)n * DP * 2);        // H1 / H2
    __half* bufR    = (__half*)carve((size_t)n * DP * 2);        // R
    __half* bufC    = (__half*)carve((size_t)n * DP * 2);        // ARMA out
    _Float16* Wt1   = (_Float16*)carve((size_t)DP * DP * 2);
    _Float16* Wt2   = (_Float16*)carve((size_t)DP * DP * 2);
    _Float16* Wt3   = (_Float16*)carve((size_t)DP * DP * 2);
    _Float16* Wt4   = (_Float16*)carve((size_t)DP * DP * 2);
    int*    off     = (int*)carve((size_t)(n + 1) * 4);
    int*    btotal  = (int*)carve((size_t)NBUK * 4);
    int*    bbase   = (int*)carve((size_t)(NBUK + 1) * 4);
    int*    bcursor = (int*)carve((size_t)NBUK * 4);
    int*    ssorted = (int*)carve((size_t)e * 4);
    unsigned int* gpairs = (unsigned int*)carve((size_t)e * 4);
    float*  dinv_sl = (float*)carve((size_t)n * 4);
    float*  dinv_nsl= (float*)carve((size_t)n * 4);
    float*  bnsum   = (float*)carve(DP * 4);
    float*  bnsq    = (float*)carve(DP * 4);
    float*  bnscale = (float*)carve(DP * 4);
    float*  bnshift = (float*)carve(DP * 4);
    float*  b1p     = (float*)carve(DP * 4);
    float*  b2p     = (float*)carve(DP * 4);
    int*    gstart  = (int*)carve((size_t)(NGRAPH + 1) * 4);

    const int nchunk = (e + BINCH - 1) / BINCH;

    // ---- pack weights + aux init (biases, counters, zero-row) ----
    packW4_kernel<<<257, 256, 0, stream>>>(W1, W2, Wa_init, Wa_root, Wt1, Wt2, Wt3, Wt4,
                                           b1, b2, b1p, b2p, btotal, bnsum, bnsq,
                                           buf0 + (size_t)n * DP);

    // ---- build CSR by dst ----
    bin_count_kernel<<<nchunk, 256, 0, stream>>>(dst, btotal, e);
    bucket_scan_kernel<<<1, 512, 0, stream>>>(btotal, bbase, bcursor, e, batch, gstart, n);
    bin_kernel<<<nchunk, 256, 0, stream>>>(src, dst, bcursor, gpairs, e);
    bucket_build_kernel<<<NBUK, 256, 0, stream>>>(gpairs, bbase, off, ssorted, dinv_sl, dinv_nsl, n, e);

    const int prop_blocks = (n + 3) / 4;
    const int mm_blocks = (n + 63) / 64;

    // ---- SGConv 1 (matmul first: prop(x)@W1 == prop(x@W1)) ----
    matmul_a32_kernel<<<mm_blocks, 256, 0, stream>>>(x, Wt1, dinv_sl, buf0, n);
    prop_kernel<<<prop_blocks, 256, 0, stream>>>(buf0, ssorted, off, dinv_sl, b1p, buf1, n);

    // ---- SGConv 2 ----
    matmul_a16_kernel<<<mm_blocks, 256, 0, stream>>>(buf1, Wt2, dinv_sl, buf0, n);
    prop_kernel<<<prop_blocks, 256, 0, stream>>>(buf0, ssorted, off, dinv_sl, b2p, buf1, n);

    // ---- BatchNorm stats + params ----
    bnstats_kernel<<<512, 512, 0, stream>>>(buf1, bnsum, bnsq, n);
    bn_prep_kernel<<<1, 128, 0, stream>>>(bnsum, bnsq, gamma, beta, bnscale, bnshift, n);

    // ---- ARMAConv: dual matmul with fused BN, then prop with fused add+relu ----
    matmul_dual_kernel<<<mm_blocks, 256, 0, stream>>>(buf1, Wt3, Wt4, ba, dinv_nsl, bnscale, bnshift, buf0, bufR, n, DIM);
    prop_arma_kernel<<<prop_blocks, 256, 0, stream>>>(buf0, ssorted, off, dinv_nsl, bufR, bufC, n);

    // ---- fused global add pool + MLP head ----
    pmlp_kernel<<<NGRAPH, 512, 0, stream>>>(bufC, gstart, Wf1, bf1, Wf2, bf2, Wf3, bf3, Wf4, bf4, out);
}